// Round 1
// baseline (1639.261 us; speedup 1.0000x reference)
//
#include <hip/hip_runtime.h>
#include <math.h>

// ---------------------------------------------------------------------------
// NTSNet forward, f32 baseline.
// Stages: anchors | permute w1/w2/w3 | backbone GEMM (x) | nav y1 GEMM(splitK)
//         | y1 reduce | raw mean | y2 conv | y3 conv | scores | NMS | crop
//         | backbone GEMM (parts) | part mean | final linear
// ---------------------------------------------------------------------------

// ---------------- anchors (faithful port of _generate_default_anchor_maps) --
__global__ __launch_bounds__(256) void anchors_kernel(int* __restrict__ anch,
                                                      float* __restrict__ areas) {
  int i = blockIdx.x * 256 + threadIdx.x;
  if (i >= 1614) return;
  int stride, oh, a, pos;
  double size, sc;
  const double C13 = 1.2599210498948732;   // 2**(1/3) (python double repr)
  const double C23 = 1.5874010519681994;   // 2**(2/3)
  if (i < 1176) {
    stride = 32; size = 48.0; oh = 14; a = i / 196; pos = i % 196;
    sc = (a / 3 == 0) ? C13 : C23;
  } else if (i < 1470) {
    int r = i - 1176; stride = 64; size = 96.0; oh = 7; a = r / 49; pos = r % 49;
    sc = (a / 3 == 0) ? C13 : C23;
  } else {
    int r = i - 1470; stride = 128; size = 192.0; oh = 4; a = r / 16; pos = r % 16;
    int si = a / 3;
    sc = (si == 0) ? 1.0 : ((si == 1) ? C13 : C23);
  }
  int ari = a % 3;
  double ar = (ari == 0) ? 0.667 : ((ari == 1) ? 1.0 : 1.5);
  int gy = pos / oh, gx = pos % oh;
  float cy = 0.5f * (float)stride + (float)(stride * gy);  // exact ints+halves
  float cx = 0.5f * (float)stride + (float)(stride * gx);
  double ss = sqrt(ar);
  double hd = (size * sc) / ss;   // python: size*sc / ar**0.5
  double wd = (size * sc) * ss;
  float hh = (float)(hd * 0.5), wh = (float)(wd * 0.5);
  float e0 = (cy - hh) + 224.0f;
  float e1 = (cx - wh) + 224.0f;
  float e2 = (cy + hh) + 224.0f;
  float e3 = (cx + wh) + 224.0f;
  int y0 = (int)e0, x0 = (int)e1, y1i = (int)e2, x1i = (int)e3;  // trunc, all >0
  anch[i * 4 + 0] = y0; anch[i * 4 + 1] = x0;
  anch[i * 4 + 2] = y1i; anch[i * 4 + 3] = x1i;
  areas[i] = (float)(y1i - y0) * (float)(x1i - x0);
}

// ---------------- weight permute: wp[o][tap][c] = w[o][c][tap] --------------
__global__ __launch_bounds__(256) void permute_w(const float* __restrict__ w,
                                                 float* __restrict__ wp,
                                                 int Cout, int Cin) {
  int idx = blockIdx.x * 256 + threadIdx.x;
  int total = Cout * 9 * Cin;
  if (idx >= total) return;
  int c = idx % Cin; int t2 = idx / Cin; int tap = t2 % 9; int o = t2 / 9;
  wp[idx] = w[(o * Cin + c) * 9 + tap];
}

// ---------------- backbone GEMM: C[m][n] = relu(bias[n]+sum A[m][k]W[n][k]) -
// M=1568, N=2048, K=3072. MODE 0: A gathered from x patches; MODE 1: A flat.
// tile 64M x 128N, BK=32, micro 4x8.
template <int MODE>
__global__ __launch_bounds__(256) void gemm_bb(const float* __restrict__ A,
                                               const float* __restrict__ W,
                                               const float* __restrict__ bias,
                                               float* __restrict__ C) {
  __shared__ float As[32][68];
  __shared__ float Bs[32][132];
  const int m0 = blockIdx.x * 64, n0 = blockIdx.y * 128;
  const int t = threadIdx.x, tx = t & 15, ty = t >> 4;
  float acc[4][8] = {};
  for (int k0 = 0; k0 < 3072; k0 += 32) {
#pragma unroll
    for (int e = 0; e < 2; ++e) {   // stage A: 64x32
      int q = t + e * 256;
      int ml = q >> 3, kk = (q & 7) << 2;
      int m = m0 + ml;
      float4 v = make_float4(0.f, 0.f, 0.f, 0.f);
      if (m < 1568) {
        int k = k0 + kk;
        if (MODE == 0) {
          int b = m / 196, pos = m % 196;
          int py = (pos / 14) * 32 + ((k >> 5) & 31);
          int px = (pos % 14) * 32 + (k & 31);
          int c = k >> 10;
          v = *(const float4*)(A + (((b * 3 + c) * 448 + py) * 448 + px));
        } else {
          v = *(const float4*)(A + (m * 3072 + k));
        }
      }
      As[kk + 0][ml] = v.x; As[kk + 1][ml] = v.y;
      As[kk + 2][ml] = v.z; As[kk + 3][ml] = v.w;
    }
#pragma unroll
    for (int e = 0; e < 4; ++e) {   // stage B: 128x32
      int q = t + e * 256;
      int nl = q >> 3, kk = (q & 7) << 2;
      float4 v = *(const float4*)(W + ((n0 + nl) * 3072 + k0 + kk));
      Bs[kk + 0][nl] = v.x; Bs[kk + 1][nl] = v.y;
      Bs[kk + 2][nl] = v.z; Bs[kk + 3][nl] = v.w;
    }
    __syncthreads();
#pragma unroll
    for (int kk = 0; kk < 32; ++kk) {
      float a[4], b[8];
      *(float4*)&a[0] = *(const float4*)&As[kk][ty * 4];
      *(float4*)&b[0] = *(const float4*)&Bs[kk][tx * 8];
      *(float4*)&b[4] = *(const float4*)&Bs[kk][tx * 8 + 4];
#pragma unroll
      for (int i = 0; i < 4; ++i)
#pragma unroll
        for (int j = 0; j < 8; ++j) acc[i][j] = fmaf(a[i], b[j], acc[i][j]);
    }
    __syncthreads();
  }
#pragma unroll
  for (int i = 0; i < 4; ++i) {
    int m = m0 + ty * 4 + i;
    if (m >= 1568) continue;
#pragma unroll
    for (int j = 0; j < 8; j += 4) {
      int n = n0 + tx * 8 + j;
      float4 v;
      v.x = fmaxf(acc[i][j + 0] + bias[n + 0], 0.f);
      v.y = fmaxf(acc[i][j + 1] + bias[n + 1], 0.f);
      v.z = fmaxf(acc[i][j + 2] + bias[n + 2], 0.f);
      v.w = fmaxf(acc[i][j + 3] + bias[n + 3], 0.f);
      *(float4*)(C + (m * 2048 + n)) = v;
    }
  }
}

// ---------------- navigator y1 GEMM: M=1568, N=128, K=9*2048, split-K=8 -----
// A gathered from raw [b][y][x][c] with 3x3 zero-pad; B = w1p[o][tap][c].
__global__ __launch_bounds__(256) void gemm_nav1(const float* __restrict__ raw,
                                                 const float* __restrict__ w1p,
                                                 float* __restrict__ part) {
  __shared__ float As[32][68];
  __shared__ float Bs[32][132];
  const int m0 = blockIdx.x * 64;
  const int sp = blockIdx.y;  // 0..7
  const int t = threadIdx.x, tx = t & 15, ty = t >> 4;
  float acc[4][8] = {};
  const int kbeg = sp * 2304, kend = kbeg + 2304;
  for (int k0 = kbeg; k0 < kend; k0 += 32) {
    const int tap = k0 >> 11;  // 2048-aligned tap regions; 32 | 2048
    const int dy = tap / 3 - 1, dx = tap % 3 - 1;
#pragma unroll
    for (int e = 0; e < 2; ++e) {  // stage A: 64x32
      int q = t + e * 256;
      int ml = q >> 3, kk = (q & 7) << 2;
      int m = m0 + ml;
      float4 v = make_float4(0.f, 0.f, 0.f, 0.f);
      if (m < 1568) {
        int b = m / 196, pos = m % 196;
        int sy = pos / 14 + dy;
        int sx = pos % 14 + dx;
        if (sy >= 0 && sy < 14 && sx >= 0 && sx < 14) {
          int c = (k0 & 2047) + kk;
          v = *(const float4*)(raw + ((b * 196 + sy * 14 + sx) * 2048 + c));
        }
      }
      As[kk + 0][ml] = v.x; As[kk + 1][ml] = v.y;
      As[kk + 2][ml] = v.z; As[kk + 3][ml] = v.w;
    }
#pragma unroll
    for (int e = 0; e < 4; ++e) {  // stage B: 128x32
      int q = t + e * 256;
      int nl = q >> 3, kk = (q & 7) << 2;
      float4 v = *(const float4*)(w1p + (nl * 18432 + k0 + kk));
      Bs[kk + 0][nl] = v.x; Bs[kk + 1][nl] = v.y;
      Bs[kk + 2][nl] = v.z; Bs[kk + 3][nl] = v.w;
    }
    __syncthreads();
#pragma unroll
    for (int kk = 0; kk < 32; ++kk) {
      float a[4], b[8];
      *(float4*)&a[0] = *(const float4*)&As[kk][ty * 4];
      *(float4*)&b[0] = *(const float4*)&Bs[kk][tx * 8];
      *(float4*)&b[4] = *(const float4*)&Bs[kk][tx * 8 + 4];
#pragma unroll
      for (int i = 0; i < 4; ++i)
#pragma unroll
        for (int j = 0; j < 8; ++j) acc[i][j] = fmaf(a[i], b[j], acc[i][j]);
    }
    __syncthreads();
  }
#pragma unroll
  for (int i = 0; i < 4; ++i) {
    int m = m0 + ty * 4 + i;
    if (m >= 1568) continue;
#pragma unroll
    for (int j = 0; j < 8; j += 4) {
      int n = tx * 8 + j;
      *(float4*)(part + ((sp * 1568 + m) * 128 + n)) =
          make_float4(acc[i][j], acc[i][j + 1], acc[i][j + 2], acc[i][j + 3]);
    }
  }
}

__global__ __launch_bounds__(256) void y1_reduce(const float* __restrict__ part,
                                                 const float* __restrict__ b1,
                                                 float* __restrict__ y1) {
  int idx = blockIdx.x * 256 + threadIdx.x;
  if (idx >= 1568 * 128) return;
  int o = idx & 127;
  float s = b1[o];
#pragma unroll
  for (int sp = 0; sp < 8; ++sp) s += part[sp * 1568 * 128 + idx];
  y1[idx] = fmaxf(s, 0.f);
}

// ---------------- small 3x3 stride-2 pad-1 convs (128->128 ch, NHWC) --------
__global__ __launch_bounds__(256) void conv3x3s2(const float* __restrict__ in,
                                                 const float* __restrict__ wp,
                                                 const float* __restrict__ bias,
                                                 float* __restrict__ out,
                                                 int Hin, int Hout) {
  int idx = blockIdx.x * 256 + threadIdx.x;
  int total = 8 * Hout * Hout * 128;
  if (idx >= total) return;
  int o = idx & 127; int pos = idx >> 7;
  int ox = pos % Hout; int t2 = pos / Hout; int oy = t2 % Hout; int b = t2 / Hout;
  float acc = bias[o];
  for (int dy = 0; dy < 3; ++dy) {
    int iy = 2 * oy - 1 + dy;
    if (iy < 0 || iy >= Hin) continue;
    for (int dx = 0; dx < 3; ++dx) {
      int ix = 2 * ox - 1 + dx;
      if (ix < 0 || ix >= Hin) continue;
      const float* ip = in + ((b * Hin + iy) * Hin + ix) * 128;
      const float* w = wp + (o * 9 + dy * 3 + dx) * 128;
#pragma unroll 4
      for (int c = 0; c < 128; c += 4) {
        float4 a = *(const float4*)(ip + c);
        float4 ww = *(const float4*)(w + c);
        acc += a.x * ww.x + a.y * ww.y + a.z * ww.z + a.w * ww.w;
      }
    }
  }
  out[idx] = fmaxf(acc, 0.f);
}

// ---------------- rpn scores ------------------------------------------------
__global__ __launch_bounds__(256) void scores_kernel(
    const float* __restrict__ y1, const float* __restrict__ y2,
    const float* __restrict__ y3, const float* __restrict__ t1w,
    const float* __restrict__ t1b, const float* __restrict__ t2w,
    const float* __restrict__ t2b, const float* __restrict__ t3w,
    const float* __restrict__ t3b, float* __restrict__ scores) {
  int idx = blockIdx.x * 256 + threadIdx.x;
  if (idx >= 8 * 1614) return;
  int b = idx / 1614, sI = idx % 1614;
  const float* f; const float* w; float bias;
  if (sI < 1176) {
    int a = sI / 196;
    f = y1 + (b * 196 + (sI % 196)) * 128; w = t1w + a * 128; bias = t1b[a];
  } else if (sI < 1470) {
    int r = sI - 1176; int a = r / 49;
    f = y2 + (b * 49 + (r % 49)) * 128; w = t2w + a * 128; bias = t2b[a];
  } else {
    int r = sI - 1470; int a = r / 16;
    f = y3 + (b * 16 + (r % 16)) * 128; w = t3w + a * 128; bias = t3b[a];
  }
  float acc = 0.f;
  for (int c = 0; c < 128; c += 4) {
    float4 a4 = *(const float4*)(f + c);
    float4 w4 = *(const float4*)(w + c);
    acc += a4.x * w4.x + a4.y * w4.y + a4.z * w4.z + a4.w * w4.w;
  }
  scores[idx] = acc + bias;
}

// ---------------- greedy NMS (per batch block) ------------------------------
__global__ __launch_bounds__(256) void nms_kernel(const float* __restrict__ scores,
                                                  const int* __restrict__ anch,
                                                  const float* __restrict__ areas,
                                                  int* __restrict__ boxes) {
  const int b = blockIdx.x, t = threadIdx.x;
  const float* s = scores + b * 1614;
  __shared__ unsigned char valid[1614];
  __shared__ float rv[256];
  __shared__ int ri[256];
  for (int i = t; i < 1614; i += 256) valid[i] = 1;
  __syncthreads();
  for (int n = 0; n < 4; ++n) {
    float best = -INFINITY; int bi = 0x7fffffff;
    for (int i = t; i < 1614; i += 256) {
      if (valid[i]) {
        float v = s[i];
        if (v > best || (v == best && i < bi)) { best = v; bi = i; }
      }
    }
    rv[t] = best; ri[t] = bi;
    __syncthreads();
    for (int off = 128; off > 0; off >>= 1) {
      if (t < off) {
        float ov = rv[t + off]; int oi = ri[t + off];
        if (ov > rv[t] || (ov == rv[t] && oi < ri[t])) { rv[t] = ov; ri[t] = oi; }
      }
      __syncthreads();
    }
    int sel = ri[0];
    if (sel > 1613) sel = 0;  // all-suppressed fallback == argmax(all -inf)=0
    const int4 bb = ((const int4*)anch)[sel];
    const float Ai = areas[sel];
    if (t == 0) ((int4*)boxes)[b * 4 + n] = bb;
    __syncthreads();
    for (int i = t; i < 1614; i += 256) {
      if (!valid[i]) continue;
      const int4 ab = ((const int4*)anch)[i];
      float sy = fmaxf((float)ab.x, (float)bb.x);
      float sx = fmaxf((float)ab.y, (float)bb.y);
      float ey = fminf((float)ab.z, (float)bb.z);
      float ex = fminf((float)ab.w, (float)bb.w);
      float ly = ey - sy, lx = ex - sx;
      float inter = (ly < 0.f || lx < 0.f) ? 0.f : ly * lx;
      float iou = inter / (areas[i] + Ai - inter);
      if (iou >= 0.25f) valid[i] = 0;
    }
    __syncthreads();
  }
}

// ---------------- bilinear crop, written in im2col patch layout -------------
__global__ __launch_bounds__(256) void crop_kernel(const float* __restrict__ x,
                                                   const int* __restrict__ boxes,
                                                   float* __restrict__ A2) {
  int idx = blockIdx.x * 256 + threadIdx.x;
  if (idx >= 32 * 3 * 224 * 224) return;
  int px = idx % 224; int t1 = idx / 224; int py = t1 % 224; int t2 = t1 / 224;
  int c = t2 % 3; int p = t2 / 3;
  int b = p >> 2;
  const int4 bb = ((const int4*)boxes)[p];
  float ty = (float)py / 223.0f;
  float txf = (float)px / 223.0f;
  float ys = (float)bb.x + ty * (float)(bb.z - bb.x - 1);
  float xs = (float)bb.y + txf * (float)(bb.w - bb.y - 1);
  float yf = floorf(ys), xf = floorf(xs);
  float wy = ys - yf, wx = xs - xf;
  int yl = (int)yf, xl = (int)xf;
  int yh = min(yl + 1, 895), xh = min(xl + 1, 895);
  const float* img = x + (size_t)(b * 3 + c) * 448 * 448;
  auto samp = [&](int yy, int xx) -> float {
    yy -= 224; xx -= 224;
    if (yy < 0 || yy >= 448 || xx < 0 || xx >= 448) return 0.f;
    return img[yy * 448 + xx];
  };
  float v00 = samp(yl, xl), v01 = samp(yl, xh);
  float v10 = samp(yh, xl), v11 = samp(yh, xh);
  float top = v00 * (1.f - wx) + v01 * wx;
  float bot = v10 * (1.f - wx) + v11 * wx;
  float val = top * (1.f - wy) + bot * wy;
  int i = py >> 5, r = py & 31, j = px >> 5, col = px & 31;
  int m = p * 49 + i * 7 + j;
  int k = (c << 10) + (r << 5) + col;
  A2[(size_t)m * 3072 + k] = val;
}

// ---------------- spatial mean: out[g][o] = mean_r in[g*rows+r][o] ----------
__global__ __launch_bounds__(256) void mean_kernel(const float* __restrict__ in,
                                                   float* __restrict__ out,
                                                   int rows) {
  int g = blockIdx.x, t = threadIdx.x;
  for (int o = t; o < 2048; o += 256) {
    float sum = 0.f;
    for (int r = 0; r < rows; ++r) sum += in[(g * rows + r) * 2048 + o];
    out[g * 2048 + o] = sum / (float)rows;
  }
}

// ---------------- final linear: one wave per (b, class) ---------------------
__global__ __launch_bounds__(256) void final_kernel(const float* __restrict__ pfeat,
                                                    const float* __restrict__ rfeat,
                                                    const float* __restrict__ cw,
                                                    const float* __restrict__ cb,
                                                    float* __restrict__ out) {
  int gw = (blockIdx.x * 256 + threadIdx.x) >> 6;
  int lane = threadIdx.x & 63;
  if (gw >= 1600) return;
  int b = gw / 200, j = gw % 200;
  const float* wr = cw + j * 10240;
  const float* pf = pfeat + b * 8192;  // pfeat rows b*4..b*4+3 are contiguous
  float acc = 0.f;
  for (int k = lane * 4; k < 8192; k += 256) {
    float4 a = *(const float4*)(pf + k);
    float4 w = *(const float4*)(wr + k);
    acc += a.x * w.x + a.y * w.y + a.z * w.z + a.w * w.w;
  }
  const float* rf = rfeat + b * 2048;
  const float* wr2 = wr + 8192;
  for (int k = lane * 4; k < 2048; k += 256) {
    float4 a = *(const float4*)(rf + k);
    float4 w = *(const float4*)(wr2 + k);
    acc += a.x * w.x + a.y * w.y + a.z * w.z + a.w * w.w;
  }
#pragma unroll
  for (int off = 32; off > 0; off >>= 1) acc += __shfl_down(acc, off, 64);
  if (lane == 0) out[b * 200 + j] = acc + cb[j];
}

// ---------------------------------------------------------------------------
extern "C" void kernel_launch(void* const* d_in, const int* in_sizes, int n_in,
                              void* d_out, int out_size, void* d_ws, size_t ws_size,
                              hipStream_t stream) {
  const float* x   = (const float*)d_in[0];
  const float* bbw = (const float*)d_in[1];
  const float* bbb = (const float*)d_in[2];
  const float* w1  = (const float*)d_in[3];
  const float* b1  = (const float*)d_in[4];
  const float* t1w = (const float*)d_in[5];
  const float* t1b = (const float*)d_in[6];
  const float* w2  = (const float*)d_in[7];
  const float* b2  = (const float*)d_in[8];
  const float* t2w = (const float*)d_in[9];
  const float* t2b = (const float*)d_in[10];
  const float* w3  = (const float*)d_in[11];
  const float* b3  = (const float*)d_in[12];
  const float* t3w = (const float*)d_in[13];
  const float* t3b = (const float*)d_in[14];
  const float* cw  = (const float*)d_in[15];
  const float* cb  = (const float*)d_in[16];
  float* out = (float*)d_out;

  char* p = (char*)d_ws;
  auto alloc = [&](size_t bytes) -> char* {
    char* r = p; p += (bytes + 255) & ~(size_t)255; return r;
  };
  int*   anch  = (int*)  alloc((size_t)1614 * 4 * 4);
  float* areas = (float*)alloc((size_t)1614 * 4);
  float* w1p   = (float*)alloc((size_t)128 * 9 * 2048 * 4);
  float* w2p   = (float*)alloc((size_t)128 * 9 * 128 * 4);
  float* w3p   = (float*)alloc((size_t)128 * 9 * 128 * 4);
  float* raw   = (float*)alloc((size_t)1568 * 2048 * 4);  // reused for part_out
  float* y1s   = (float*)alloc((size_t)8 * 1568 * 128 * 4);
  float* y1v   = (float*)alloc((size_t)1568 * 128 * 4);
  float* y2v   = (float*)alloc((size_t)392 * 128 * 4);
  float* y3v   = (float*)alloc((size_t)128 * 128 * 4);
  float* sc    = (float*)alloc((size_t)8 * 1614 * 4);
  int*   boxes = (int*)  alloc((size_t)8 * 4 * 4 * 4);
  float* A2    = (float*)alloc((size_t)1568 * 3072 * 4);
  float* pfeat = (float*)alloc((size_t)32 * 2048 * 4);
  float* rfeat = (float*)alloc((size_t)8 * 2048 * 4);

  anchors_kernel<<<7, 256, 0, stream>>>(anch, areas);
  permute_w<<<(128 * 9 * 2048 + 255) / 256, 256, 0, stream>>>(w1, w1p, 128, 2048);
  permute_w<<<(128 * 9 * 128 + 255) / 256, 256, 0, stream>>>(w2, w2p, 128, 128);
  permute_w<<<(128 * 9 * 128 + 255) / 256, 256, 0, stream>>>(w3, w3p, 128, 128);

  gemm_bb<0><<<dim3(25, 16), 256, 0, stream>>>(x, bbw, bbb, raw);
  gemm_nav1<<<dim3(25, 8), 256, 0, stream>>>(raw, w1p, y1s);
  y1_reduce<<<(1568 * 128 + 255) / 256, 256, 0, stream>>>(y1s, b1, y1v);
  mean_kernel<<<8, 256, 0, stream>>>(raw, rfeat, 196);
  conv3x3s2<<<(8 * 7 * 7 * 128 + 255) / 256, 256, 0, stream>>>(y1v, w2p, b2, y2v, 14, 7);
  conv3x3s2<<<(8 * 4 * 4 * 128 + 255) / 256, 256, 0, stream>>>(y2v, w3p, b3, y3v, 7, 4);
  scores_kernel<<<(8 * 1614 + 255) / 256, 256, 0, stream>>>(
      y1v, y2v, y3v, t1w, t1b, t2w, t2b, t3w, t3b, sc);
  nms_kernel<<<8, 256, 0, stream>>>(sc, anch, areas, boxes);
  crop_kernel<<<(32 * 3 * 224 * 224) / 256, 256, 0, stream>>>(x, boxes, A2);
  gemm_bb<1><<<dim3(25, 16), 256, 0, stream>>>(A2, bbw, bbb, raw);
  mean_kernel<<<32, 256, 0, stream>>>(raw, pfeat, 49);
  final_kernel<<<400, 256, 0, stream>>>(pfeat, rfeat, cw, cb, out);
}

// Round 2
// 938.035 us; speedup vs baseline: 1.7475x; 1.7475x over previous
//
#include <hip/hip_runtime.h>
#include <math.h>

// ---------------------------------------------------------------------------
// NTSNet forward. Big GEMMs on MFMA via 2-way f16 split (3 products: hh,hl,lh)
// ---------------------------------------------------------------------------

typedef _Float16 h8 __attribute__((ext_vector_type(8)));
typedef float f32x4 __attribute__((ext_vector_type(4)));

#define ASCALE 256.0f
#define WSCALE 16384.0f
#define RSCALE (1.0f / (256.0f * 16384.0f))

__device__ __forceinline__ void gload16(const void* g, void* l) {
  __builtin_amdgcn_global_load_lds(
      (__attribute__((address_space(1))) void*)(void*)(uintptr_t)g,
      (__attribute__((address_space(3))) void*)l, 16, 0, 0);
}

// ---------------- anchors (faithful port of _generate_default_anchor_maps) --
__global__ __launch_bounds__(256) void anchors_kernel(int* __restrict__ anch,
                                                      float* __restrict__ areas) {
  int i = blockIdx.x * 256 + threadIdx.x;
  if (i >= 1614) return;
  int stride, oh, a, pos;
  double size, sc;
  const double C13 = 1.2599210498948732;
  const double C23 = 1.5874010519681994;
  if (i < 1176) {
    stride = 32; size = 48.0; oh = 14; a = i / 196; pos = i % 196;
    sc = (a / 3 == 0) ? C13 : C23;
  } else if (i < 1470) {
    int r = i - 1176; stride = 64; size = 96.0; oh = 7; a = r / 49; pos = r % 49;
    sc = (a / 3 == 0) ? C13 : C23;
  } else {
    int r = i - 1470; stride = 128; size = 192.0; oh = 4; a = r / 16; pos = r % 16;
    int si = a / 3;
    sc = (si == 0) ? 1.0 : ((si == 1) ? C13 : C23);
  }
  int ari = a % 3;
  double ar = (ari == 0) ? 0.667 : ((ari == 1) ? 1.0 : 1.5);
  int gy = pos / oh, gx = pos % oh;
  float cy = 0.5f * (float)stride + (float)(stride * gy);
  float cx = 0.5f * (float)stride + (float)(stride * gx);
  double ss = sqrt(ar);
  double hd = (size * sc) / ss;
  double wd = (size * sc) * ss;
  float hh = (float)(hd * 0.5), wh = (float)(wd * 0.5);
  float e0 = (cy - hh) + 224.0f;
  float e1 = (cx - wh) + 224.0f;
  float e2 = (cy + hh) + 224.0f;
  float e3 = (cx + wh) + 224.0f;
  int y0 = (int)e0, x0 = (int)e1, y1i = (int)e2, x1i = (int)e3;
  anch[i * 4 + 0] = y0; anch[i * 4 + 1] = x0;
  anch[i * 4 + 2] = y1i; anch[i * 4 + 3] = x1i;
  areas[i] = (float)(y1i - y0) * (float)(x1i - x0);
}

// ---------------- weight permute: wp[o][tap][c] = w[o][c][tap] --------------
__global__ __launch_bounds__(256) void permute_w(const float* __restrict__ w,
                                                 float* __restrict__ wp,
                                                 int Cout, int Cin) {
  int idx = blockIdx.x * 256 + threadIdx.x;
  int total = Cout * 9 * Cin;
  if (idx >= total) return;
  int c = idx % Cin; int t2 = idx / Cin; int tap = t2 % 9; int o = t2 / 9;
  wp[idx] = w[(o * Cin + c) * 9 + tap];
}

// ---------------- f32 -> f16 hi/lo split (linear, scale WSCALE) -------------
__global__ __launch_bounds__(256) void split_w(const float* __restrict__ src,
                                               _Float16* __restrict__ h,
                                               _Float16* __restrict__ l, int n8) {
  int i = blockIdx.x * 256 + threadIdx.x;
  if (i >= n8) return;
  float4 v0 = *(const float4*)(src + (size_t)i * 8);
  float4 v1 = *(const float4*)(src + (size_t)i * 8 + 4);
  float vv[8] = {v0.x, v0.y, v0.z, v0.w, v1.x, v1.y, v1.z, v1.w};
  h8 vh, vl;
#pragma unroll
  for (int j = 0; j < 8; ++j) {
    float s = vv[j] * WSCALE;
    _Float16 a = (_Float16)s;
    vh[j] = a; vl[j] = (_Float16)(s - (float)a);
  }
  *(h8*)(h + (size_t)i * 8) = vh;
  *(h8*)(l + (size_t)i * 8) = vl;
}

// ---------------- x patchify -> A hi/lo [1664][3072] (scale ASCALE) ---------
__global__ __launch_bounds__(256) void split_x(const float* __restrict__ x,
                                               _Float16* __restrict__ Ah,
                                               _Float16* __restrict__ Al) {
  int i = blockIdx.x * 256 + threadIdx.x;
  if (i >= 1664 * 384) return;
  int kq = i % 384, m = i / 384;
  int k = kq * 8;
  h8 vh = {}, vl = {};
  if (m < 1568) {
    int b = m / 196, pos = m % 196;
    int c = k >> 10, r = (k >> 5) & 31, col = k & 31;
    int py = (pos / 14) * 32 + r, px = (pos % 14) * 32 + col;
    const float* sp2 = x + (((size_t)(b * 3 + c) * 448 + py) * 448 + px);
    float4 v0 = *(const float4*)sp2;
    float4 v1 = *(const float4*)(sp2 + 4);
    float vv[8] = {v0.x, v0.y, v0.z, v0.w, v1.x, v1.y, v1.z, v1.w};
#pragma unroll
    for (int j = 0; j < 8; ++j) {
      float s = vv[j] * ASCALE;
      _Float16 a = (_Float16)s;
      vh[j] = a; vl[j] = (_Float16)(s - (float)a);
    }
  }
  *(h8*)(Ah + (size_t)m * 3072 + k) = vh;
  *(h8*)(Al + (size_t)m * 3072 + k) = vl;
}

// ---------------- raw f32 [1568][2048] -> hi/lo [1664][2048] ----------------
__global__ __launch_bounds__(256) void split_raw(const float* __restrict__ raw,
                                                 _Float16* __restrict__ h,
                                                 _Float16* __restrict__ l) {
  int i = blockIdx.x * 256 + threadIdx.x;
  if (i >= 1664 * 256) return;
  int m = i / 256, kq = i % 256;
  int k = kq * 8;
  h8 vh = {}, vl = {};
  if (m < 1568) {
    float4 v0 = *(const float4*)(raw + (size_t)m * 2048 + k);
    float4 v1 = *(const float4*)(raw + (size_t)m * 2048 + k + 4);
    float vv[8] = {v0.x, v0.y, v0.z, v0.w, v1.x, v1.y, v1.z, v1.w};
#pragma unroll
    for (int j = 0; j < 8; ++j) {
      float s = vv[j] * ASCALE;
      _Float16 a = (_Float16)s;
      vh[j] = a; vl[j] = (_Float16)(s - (float)a);
    }
  }
  *(h8*)(h + (size_t)m * 2048 + k) = vh;
  *(h8*)(l + (size_t)m * 2048 + k) = vl;
}

// ---------------- backbone GEMM (MFMA, f16-split 3-product) -----------------
// C[m][n] = relu(bias[n] + RSCALE * sum_k A[m][k]*W[n][k]),
// A: [1664][3072] hi/lo, W: [2048][3072] hi/lo, C: [1568][2048] f32.
// LDS tiles 128x32 f16, XOR-swizzle (byte bits 4-5 ^= bits 7-8, involution).
__global__ __launch_bounds__(256) void gemm_bb_mfma(
    const _Float16* __restrict__ Ah, const _Float16* __restrict__ Al,
    const _Float16* __restrict__ Bh, const _Float16* __restrict__ Bl,
    const float* __restrict__ bias, float* __restrict__ C) {
  __shared__ __align__(16) char lds[32768];  // Ah|Al|Bh|Bl tiles, 8KB each
  const int t = threadIdx.x;
  const int m0 = blockIdx.x * 128, n0 = blockIdx.y * 128;
  const int lane = t & 63, w = t >> 6;
  const int wm = (w >> 1) * 64, wn = (w & 1) * 64;
  const int lrow = lane & 15, kg = lane >> 4;

  int offA[4], offB[4];
#pragma unroll
  for (int i = 0; i < 4; ++i) {
    int ba = (wm + i * 16 + lrow) * 64 + kg * 16;
    offA[i] = ba ^ (((ba >> 7) & 3) << 4);
    int bb2 = (wn + i * 16 + lrow) * 64 + kg * 16;
    offB[i] = bb2 ^ (((bb2 >> 7) & 3) << 4);
  }
  size_t gAo[2], gBo[2];
  int ldso[2];
#pragma unroll
  for (int e = 0; e < 2; ++e) {
    int p = e * 256 + t;
    int lsl = p ^ ((p >> 3) & 3);   // inverse swizzle (involution) in slot units
    int row = lsl >> 2, kq = lsl & 3;
    gAo[e] = (size_t)(m0 + row) * 3072 + kq * 8;
    gBo[e] = (size_t)(n0 + row) * 3072 + kq * 8;
    ldso[e] = e * 4096 + (t & 192) * 16;
  }

  f32x4 acc[4][4] = {};
  for (int k0 = 0; k0 < 3072; k0 += 32) {
#pragma unroll
    for (int e = 0; e < 2; ++e) {
      gload16(Ah + gAo[e] + k0, lds + ldso[e]);
      gload16(Al + gAo[e] + k0, lds + 8192 + ldso[e]);
      gload16(Bh + gBo[e] + k0, lds + 16384 + ldso[e]);
      gload16(Bl + gBo[e] + k0, lds + 24576 + ldso[e]);
    }
    __syncthreads();
    h8 fah[4], fal[4], fbh[4], fbl[4];
#pragma unroll
    for (int i = 0; i < 4; ++i) {
      fah[i] = *(const h8*)(lds + offA[i]);
      fal[i] = *(const h8*)(lds + 8192 + offA[i]);
      fbh[i] = *(const h8*)(lds + 16384 + offB[i]);
      fbl[i] = *(const h8*)(lds + 24576 + offB[i]);
    }
#pragma unroll
    for (int i = 0; i < 4; ++i)
#pragma unroll
      for (int j = 0; j < 4; ++j)
        acc[i][j] = __builtin_amdgcn_mfma_f32_16x16x32_f16(fah[i], fbh[j], acc[i][j], 0, 0, 0);
#pragma unroll
    for (int i = 0; i < 4; ++i)
#pragma unroll
      for (int j = 0; j < 4; ++j)
        acc[i][j] = __builtin_amdgcn_mfma_f32_16x16x32_f16(fah[i], fbl[j], acc[i][j], 0, 0, 0);
#pragma unroll
    for (int i = 0; i < 4; ++i)
#pragma unroll
      for (int j = 0; j < 4; ++j)
        acc[i][j] = __builtin_amdgcn_mfma_f32_16x16x32_f16(fal[i], fbh[j], acc[i][j], 0, 0, 0);
    __syncthreads();
  }
  const int prow = (lane >> 4) * 4;
#pragma unroll
  for (int i = 0; i < 4; ++i) {
#pragma unroll
    for (int j = 0; j < 4; ++j) {
      int n = n0 + wn + j * 16 + lrow;
      float bn = bias[n];
#pragma unroll
      for (int r = 0; r < 4; ++r) {
        int m = m0 + wm + i * 16 + prow + r;
        if (m < 1568)
          C[(size_t)m * 2048 + n] = fmaxf(fmaf(acc[i][j][r], RSCALE, bn), 0.f);
      }
    }
  }
}

// ---------------- navigator y1 GEMM (MFMA f16-split, split-K=16) ------------
// A gathered (im2col 3x3 pad 1) from rawh/rawl [1664][2048]; rows>=1568 zero.
// B = w1 split [128][18432]. part[sp][1568][128] f32 partials.
__global__ __launch_bounds__(256) void gemm_nav_mfma(
    const _Float16* __restrict__ Ah, const _Float16* __restrict__ Al,
    const _Float16* __restrict__ Bh, const _Float16* __restrict__ Bl,
    float* __restrict__ part) {
  __shared__ __align__(16) char lds[32768];
  const int t = threadIdx.x;
  const int m0 = blockIdx.x * 128;
  const int sp = blockIdx.y;  // 0..15
  const int lane = t & 63, w = t >> 6;
  const int wm = (w >> 1) * 64, wn = (w & 1) * 64;
  const int lrow = lane & 15, kg = lane >> 4;

  int offA[4], offB[4];
#pragma unroll
  for (int i = 0; i < 4; ++i) {
    int ba = (wm + i * 16 + lrow) * 64 + kg * 16;
    offA[i] = ba ^ (((ba >> 7) & 3) << 4);
    int bb2 = (wn + i * 16 + lrow) * 64 + kg * 16;
    offB[i] = bb2 ^ (((bb2 >> 7) & 3) << 4);
  }
  size_t gBo[2];
  int ldso[2], akq8[2], ab[2], apy[2], apx[2], amv[2];
#pragma unroll
  for (int e = 0; e < 2; ++e) {
    int p = e * 256 + t;
    int lsl = p ^ ((p >> 3) & 3);
    int row = lsl >> 2, kq = lsl & 3;
    gBo[e] = (size_t)row * 18432 + kq * 8;
    ldso[e] = e * 4096 + (t & 192) * 16;
    int m = m0 + row;
    amv[e] = (m < 1568);
    int b = m / 196, pos = m % 196;
    ab[e] = b; apy[e] = pos / 14; apx[e] = pos % 14;
    akq8[e] = kq * 8;
  }

  f32x4 acc[4][4] = {};
  const int kbeg = sp * 1152, kend = kbeg + 1152;
  for (int k0 = kbeg; k0 < kend; k0 += 32) {
    const int tap = k0 >> 11;
    const int c = k0 & 2047;
    const int dy = tap / 3 - 1, dx = tap % 3 - 1;
#pragma unroll
    for (int e = 0; e < 2; ++e) {
      int sy = apy[e] + dy, sx = apx[e] + dx;
      bool ok = amv[e] && ((unsigned)sy < 14u) && ((unsigned)sx < 14u);
      size_t rowi = ok ? (size_t)(ab[e] * 196 + sy * 14 + sx) : (size_t)1600;
      size_t ao = rowi * 2048 + c + akq8[e];
      gload16(Ah + ao, lds + ldso[e]);
      gload16(Al + ao, lds + 8192 + ldso[e]);
      gload16(Bh + gBo[e] + k0, lds + 16384 + ldso[e]);
      gload16(Bl + gBo[e] + k0, lds + 24576 + ldso[e]);
    }
    __syncthreads();
    h8 fah[4], fal[4], fbh[4], fbl[4];
#pragma unroll
    for (int i = 0; i < 4; ++i) {
      fah[i] = *(const h8*)(lds + offA[i]);
      fal[i] = *(const h8*)(lds + 8192 + offA[i]);
      fbh[i] = *(const h8*)(lds + 16384 + offB[i]);
      fbl[i] = *(const h8*)(lds + 24576 + offB[i]);
    }
#pragma unroll
    for (int i = 0; i < 4; ++i)
#pragma unroll
      for (int j = 0; j < 4; ++j)
        acc[i][j] = __builtin_amdgcn_mfma_f32_16x16x32_f16(fah[i], fbh[j], acc[i][j], 0, 0, 0);
#pragma unroll
    for (int i = 0; i < 4; ++i)
#pragma unroll
      for (int j = 0; j < 4; ++j)
        acc[i][j] = __builtin_amdgcn_mfma_f32_16x16x32_f16(fah[i], fbl[j], acc[i][j], 0, 0, 0);
#pragma unroll
    for (int i = 0; i < 4; ++i)
#pragma unroll
      for (int j = 0; j < 4; ++j)
        acc[i][j] = __builtin_amdgcn_mfma_f32_16x16x32_f16(fal[i], fbh[j], acc[i][j], 0, 0, 0);
    __syncthreads();
  }
  const int prow = (lane >> 4) * 4;
#pragma unroll
  for (int i = 0; i < 4; ++i) {
#pragma unroll
    for (int j = 0; j < 4; ++j) {
      int n = wn + j * 16 + lrow;
#pragma unroll
      for (int r = 0; r < 4; ++r) {
        int m = m0 + wm + i * 16 + prow + r;
        if (m < 1568)
          part[((size_t)sp * 1568 + m) * 128 + n] = acc[i][j][r] * RSCALE;
      }
    }
  }
}

__global__ __launch_bounds__(256) void y1_reduce(const float* __restrict__ part,
                                                 const float* __restrict__ b1,
                                                 float* __restrict__ y1) {
  int idx = blockIdx.x * 256 + threadIdx.x;
  if (idx >= 1568 * 128) return;
  int o = idx & 127;
  float s = b1[o];
#pragma unroll
  for (int sp = 0; sp < 16; ++sp) s += part[(size_t)sp * 1568 * 128 + idx];
  y1[idx] = fmaxf(s, 0.f);
}

// ---------------- small 3x3 stride-2 pad-1 convs (128->128 ch, NHWC) --------
__global__ __launch_bounds__(256) void conv3x3s2(const float* __restrict__ in,
                                                 const float* __restrict__ wp,
                                                 const float* __restrict__ bias,
                                                 float* __restrict__ out,
                                                 int Hin, int Hout) {
  int idx = blockIdx.x * 256 + threadIdx.x;
  int total = 8 * Hout * Hout * 128;
  if (idx >= total) return;
  int o = idx & 127; int pos = idx >> 7;
  int ox = pos % Hout; int t2 = pos / Hout; int oy = t2 % Hout; int b = t2 / Hout;
  float acc = bias[o];
  for (int dy = 0; dy < 3; ++dy) {
    int iy = 2 * oy - 1 + dy;
    if (iy < 0 || iy >= Hin) continue;
    for (int dx = 0; dx < 3; ++dx) {
      int ix = 2 * ox - 1 + dx;
      if (ix < 0 || ix >= Hin) continue;
      const float* ip = in + ((b * Hin + iy) * Hin + ix) * 128;
      const float* wgt = wp + (o * 9 + dy * 3 + dx) * 128;
#pragma unroll 4
      for (int c = 0; c < 128; c += 4) {
        float4 a = *(const float4*)(ip + c);
        float4 ww = *(const float4*)(wgt + c);
        acc += a.x * ww.x + a.y * ww.y + a.z * ww.z + a.w * ww.w;
      }
    }
  }
  out[idx] = fmaxf(acc, 0.f);
}

// ---------------- rpn scores ------------------------------------------------
__global__ __launch_bounds__(256) void scores_kernel(
    const float* __restrict__ y1, const float* __restrict__ y2,
    const float* __restrict__ y3, const float* __restrict__ t1w,
    const float* __restrict__ t1b, const float* __restrict__ t2w,
    const float* __restrict__ t2b, const float* __restrict__ t3w,
    const float* __restrict__ t3b, float* __restrict__ scores) {
  int idx = blockIdx.x * 256 + threadIdx.x;
  if (idx >= 8 * 1614) return;
  int b = idx / 1614, sI = idx % 1614;
  const float* f; const float* w; float bias;
  if (sI < 1176) {
    int a = sI / 196;
    f = y1 + (b * 196 + (sI % 196)) * 128; w = t1w + a * 128; bias = t1b[a];
  } else if (sI < 1470) {
    int r = sI - 1176; int a = r / 49;
    f = y2 + (b * 49 + (r % 49)) * 128; w = t2w + a * 128; bias = t2b[a];
  } else {
    int r = sI - 1470; int a = r / 16;
    f = y3 + (b * 16 + (r % 16)) * 128; w = t3w + a * 128; bias = t3b[a];
  }
  float acc = 0.f;
  for (int c = 0; c < 128; c += 4) {
    float4 a4 = *(const float4*)(f + c);
    float4 w4 = *(const float4*)(w + c);
    acc += a4.x * w4.x + a4.y * w4.y + a4.z * w4.z + a4.w * w4.w;
  }
  scores[idx] = acc + bias;
}

// ---------------- greedy NMS (per batch block) ------------------------------
__global__ __launch_bounds__(256) void nms_kernel(const float* __restrict__ scores,
                                                  const int* __restrict__ anch,
                                                  const float* __restrict__ areas,
                                                  int* __restrict__ boxes) {
  const int b = blockIdx.x, t = threadIdx.x;
  const float* s = scores + b * 1614;
  __shared__ unsigned char valid[1614];
  __shared__ float rv[256];
  __shared__ int ri[256];
  for (int i = t; i < 1614; i += 256) valid[i] = 1;
  __syncthreads();
  for (int n = 0; n < 4; ++n) {
    float best = -INFINITY; int bi = 0x7fffffff;
    for (int i = t; i < 1614; i += 256) {
      if (valid[i]) {
        float v = s[i];
        if (v > best || (v == best && i < bi)) { best = v; bi = i; }
      }
    }
    rv[t] = best; ri[t] = bi;
    __syncthreads();
    for (int off = 128; off > 0; off >>= 1) {
      if (t < off) {
        float ov = rv[t + off]; int oi = ri[t + off];
        if (ov > rv[t] || (ov == rv[t] && oi < ri[t])) { rv[t] = ov; ri[t] = oi; }
      }
      __syncthreads();
    }
    int sel = ri[0];
    if (sel > 1613) sel = 0;
    const int4 bb = ((const int4*)anch)[sel];
    const float Ai = areas[sel];
    if (t == 0) ((int4*)boxes)[b * 4 + n] = bb;
    __syncthreads();
    for (int i = t; i < 1614; i += 256) {
      if (!valid[i]) continue;
      const int4 ab = ((const int4*)anch)[i];
      float sy = fmaxf((float)ab.x, (float)bb.x);
      float sx = fmaxf((float)ab.y, (float)bb.y);
      float ey = fminf((float)ab.z, (float)bb.z);
      float ex = fminf((float)ab.w, (float)bb.w);
      float ly = ey - sy, lx = ex - sx;
      float inter = (ly < 0.f || lx < 0.f) ? 0.f : ly * lx;
      float iou = inter / (areas[i] + Ai - inter);
      if (iou >= 0.25f) valid[i] = 0;
    }
    __syncthreads();
  }
}

// ---------------- bilinear crop -> A hi/lo (im2col layout, scaled) ----------
__global__ __launch_bounds__(256) void crop_kernel(const float* __restrict__ x,
                                                   const int* __restrict__ boxes,
                                                   _Float16* __restrict__ Ah,
                                                   _Float16* __restrict__ Al) {
  int idx = blockIdx.x * 256 + threadIdx.x;
  if (idx >= 32 * 3 * 224 * 224) return;
  int px = idx % 224; int t1 = idx / 224; int py = t1 % 224; int t2 = t1 / 224;
  int c = t2 % 3; int p = t2 / 3;
  int b = p >> 2;
  const int4 bb = ((const int4*)boxes)[p];
  float ty = (float)py / 223.0f;
  float txf = (float)px / 223.0f;
  float ys = (float)bb.x + ty * (float)(bb.z - bb.x - 1);
  float xs = (float)bb.y + txf * (float)(bb.w - bb.y - 1);
  float yf = floorf(ys), xf = floorf(xs);
  float wy = ys - yf, wx = xs - xf;
  int yl = (int)yf, xl = (int)xf;
  int yh = min(yl + 1, 895), xh = min(xl + 1, 895);
  const float* img = x + (size_t)(b * 3 + c) * 448 * 448;
  auto samp = [&](int yy, int xx) -> float {
    yy -= 224; xx -= 224;
    if (yy < 0 || yy >= 448 || xx < 0 || xx >= 448) return 0.f;
    return img[yy * 448 + xx];
  };
  float v00 = samp(yl, xl), v01 = samp(yl, xh);
  float v10 = samp(yh, xl), v11 = samp(yh, xh);
  float top = v00 * (1.f - wx) + v01 * wx;
  float bot = v10 * (1.f - wx) + v11 * wx;
  float val = top * (1.f - wy) + bot * wy;
  int i = py >> 5, r = py & 31, j = px >> 5, col = px & 31;
  int m = p * 49 + i * 7 + j;
  int k = (c << 10) + (r << 5) + col;
  float s = val * ASCALE;
  _Float16 a = (_Float16)s;
  Ah[(size_t)m * 3072 + k] = a;
  Al[(size_t)m * 3072 + k] = (_Float16)(s - (float)a);
}

// ---------------- spatial mean: out[g][o] = mean_r in[g*rows+r][o] ----------
__global__ __launch_bounds__(256) void mean_kernel(const float* __restrict__ in,
                                                   float* __restrict__ out,
                                                   int rows) {
  int g = blockIdx.x, t = threadIdx.x;
  for (int o = t; o < 2048; o += 256) {
    float sum = 0.f;
    for (int r = 0; r < rows; ++r) sum += in[((size_t)g * rows + r) * 2048 + o];
    out[(size_t)g * 2048 + o] = sum / (float)rows;
  }
}

// ---------------- final linear: one wave per (b, class) ---------------------
__global__ __launch_bounds__(256) void final_kernel(const float* __restrict__ pfeat,
                                                    const float* __restrict__ rfeat,
                                                    const float* __restrict__ cw,
                                                    const float* __restrict__ cb,
                                                    float* __restrict__ out) {
  int gw = (blockIdx.x * 256 + threadIdx.x) >> 6;
  int lane = threadIdx.x & 63;
  if (gw >= 1600) return;
  int b = gw / 200, j = gw % 200;
  const float* wr = cw + (size_t)j * 10240;
  const float* pf = pfeat + (size_t)b * 8192;
  float acc = 0.f;
  for (int k = lane * 4; k < 8192; k += 256) {
    float4 a = *(const float4*)(pf + k);
    float4 w = *(const float4*)(wr + k);
    acc += a.x * w.x + a.y * w.y + a.z * w.z + a.w * w.w;
  }
  const float* rf = rfeat + (size_t)b * 2048;
  const float* wr2 = wr + 8192;
  for (int k = lane * 4; k < 2048; k += 256) {
    float4 a = *(const float4*)(rf + k);
    float4 w = *(const float4*)(wr2 + k);
    acc += a.x * w.x + a.y * w.y + a.z * w.z + a.w * w.w;
  }
#pragma unroll
  for (int off = 32; off > 0; off >>= 1) acc += __shfl_down(acc, off, 64);
  if (lane == 0) out[b * 200 + j] = acc + cb[j];
}

// ---------------------------------------------------------------------------
extern "C" void kernel_launch(void* const* d_in, const int* in_sizes, int n_in,
                              void* d_out, int out_size, void* d_ws, size_t ws_size,
                              hipStream_t stream) {
  const float* x   = (const float*)d_in[0];
  const float* bbw = (const float*)d_in[1];
  const float* bbb = (const float*)d_in[2];
  const float* w1  = (const float*)d_in[3];
  const float* b1  = (const float*)d_in[4];
  const float* t1w = (const float*)d_in[5];
  const float* t1b = (const float*)d_in[6];
  const float* w2  = (const float*)d_in[7];
  const float* b2  = (const float*)d_in[8];
  const float* t2w = (const float*)d_in[9];
  const float* t2b = (const float*)d_in[10];
  const float* w3  = (const float*)d_in[11];
  const float* b3  = (const float*)d_in[12];
  const float* t3w = (const float*)d_in[13];
  const float* t3b = (const float*)d_in[14];
  const float* cw  = (const float*)d_in[15];
  const float* cb  = (const float*)d_in[16];
  float* out = (float*)d_out;

  char* p = (char*)d_ws;
  auto alloc = [&](size_t bytes) -> char* {
    char* r = p; p += (bytes + 255) & ~(size_t)255; return r;
  };
  int*      anch  = (int*)     alloc((size_t)1614 * 4 * 4);
  float*    areas = (float*)   alloc((size_t)1614 * 4);
  float*    w1p   = (float*)   alloc((size_t)128 * 18432 * 4);
  _Float16* bWh   = (_Float16*)alloc((size_t)2048 * 3072 * 2);
  _Float16* bWl   = (_Float16*)alloc((size_t)2048 * 3072 * 2);
  _Float16* w1h   = (_Float16*)alloc((size_t)128 * 18432 * 2);
  _Float16* w1l   = (_Float16*)alloc((size_t)128 * 18432 * 2);
  _Float16* Ahh   = (_Float16*)alloc((size_t)1664 * 3072 * 2);
  _Float16* All   = (_Float16*)alloc((size_t)1664 * 3072 * 2);
  _Float16* rawh  = (_Float16*)alloc((size_t)1664 * 2048 * 2);
  _Float16* rawl  = (_Float16*)alloc((size_t)1664 * 2048 * 2);
  float*    raw   = (float*)   alloc((size_t)1568 * 2048 * 4);
  float*    w2p   = (float*)   alloc((size_t)128 * 9 * 128 * 4);
  float*    w3p   = (float*)   alloc((size_t)128 * 9 * 128 * 4);
  float*    y1s   = (float*)   alloc((size_t)16 * 1568 * 128 * 4);
  float*    y1v   = (float*)   alloc((size_t)1568 * 128 * 4);
  float*    y2v   = (float*)   alloc((size_t)392 * 128 * 4);
  float*    y3v   = (float*)   alloc((size_t)128 * 128 * 4);
  float*    sc    = (float*)   alloc((size_t)8 * 1614 * 4);
  int*      boxes = (int*)     alloc((size_t)8 * 4 * 4 * 4);
  float*    pfeat = (float*)   alloc((size_t)32 * 2048 * 4);
  float*    rfeat = (float*)   alloc((size_t)8 * 2048 * 4);

  anchors_kernel<<<7, 256, 0, stream>>>(anch, areas);
  permute_w<<<(128 * 9 * 2048 + 255) / 256, 256, 0, stream>>>(w1, w1p, 128, 2048);
  permute_w<<<(128 * 9 * 128 + 255) / 256, 256, 0, stream>>>(w2, w2p, 128, 128);
  permute_w<<<(128 * 9 * 128 + 255) / 256, 256, 0, stream>>>(w3, w3p, 128, 128);
  split_w<<<(2048 * 3072 / 8 + 255) / 256, 256, 0, stream>>>(bbw, bWh, bWl, 2048 * 3072 / 8);
  split_w<<<(128 * 18432 / 8 + 255) / 256, 256, 0, stream>>>(w1p, w1h, w1l, 128 * 18432 / 8);
  split_x<<<(1664 * 384 + 255) / 256, 256, 0, stream>>>(x, Ahh, All);

  gemm_bb_mfma<<<dim3(13, 16), 256, 0, stream>>>(Ahh, All, bWh, bWl, bbb, raw);
  split_raw<<<(1664 * 256 + 255) / 256, 256, 0, stream>>>(raw, rawh, rawl);
  gemm_nav_mfma<<<dim3(13, 16), 256, 0, stream>>>(rawh, rawl, w1h, w1l, y1s);
  y1_reduce<<<(1568 * 128 + 255) / 256, 256, 0, stream>>>(y1s, b1, y1v);
  mean_kernel<<<8, 256, 0, stream>>>(raw, rfeat, 196);
  conv3x3s2<<<(8 * 7 * 7 * 128 + 255) / 256, 256, 0, stream>>>(y1v, w2p, b2, y2v, 14, 7);
  conv3x3s2<<<(8 * 4 * 4 * 128 + 255) / 256, 256, 0, stream>>>(y2v, w3p, b3, y3v, 7, 4);
  scores_kernel<<<(8 * 1614 + 255) / 256, 256, 0, stream>>>(
      y1v, y2v, y3v, t1w, t1b, t2w, t2b, t3w, t3b, sc);
  nms_kernel<<<8, 256, 0, stream>>>(sc, anch, areas, boxes);
  crop_kernel<<<(32 * 3 * 224 * 224) / 256, 256, 0, stream>>>(x, boxes, Ahh, All);
  gemm_bb_mfma<<<dim3(13, 16), 256, 0, stream>>>(Ahh, All, bWh, bWl, bbb, raw);
  mean_kernel<<<32, 256, 0, stream>>>(raw, pfeat, 49);
  final_kernel<<<400, 256, 0, stream>>>(pfeat, rfeat, cw, cb, out);
}

// Round 3
// 503.630 us; speedup vs baseline: 3.2549x; 1.8625x over previous
//
#include <hip/hip_runtime.h>
#include <math.h>

// ---------------------------------------------------------------------------
// NTSNet forward. Big GEMMs on MFMA via 2-way f16 split (3 products: hh,hl,lh)
// R2: parallel mean kernels (were 734us of 938us due to 8/32-block launches).
// ---------------------------------------------------------------------------

typedef _Float16 h8 __attribute__((ext_vector_type(8)));
typedef float f32x4 __attribute__((ext_vector_type(4)));

#define ASCALE 256.0f
#define WSCALE 16384.0f
#define RSCALE (1.0f / (256.0f * 16384.0f))

__device__ __forceinline__ void gload16(const void* g, void* l) {
  __builtin_amdgcn_global_load_lds(
      (__attribute__((address_space(1))) void*)(void*)(uintptr_t)g,
      (__attribute__((address_space(3))) void*)l, 16, 0, 0);
}

// ---------------- anchors (faithful port of _generate_default_anchor_maps) --
__global__ __launch_bounds__(256) void anchors_kernel(int* __restrict__ anch,
                                                      float* __restrict__ areas) {
  int i = blockIdx.x * 256 + threadIdx.x;
  if (i >= 1614) return;
  int stride, oh, a, pos;
  double size, sc;
  const double C13 = 1.2599210498948732;
  const double C23 = 1.5874010519681994;
  if (i < 1176) {
    stride = 32; size = 48.0; oh = 14; a = i / 196; pos = i % 196;
    sc = (a / 3 == 0) ? C13 : C23;
  } else if (i < 1470) {
    int r = i - 1176; stride = 64; size = 96.0; oh = 7; a = r / 49; pos = r % 49;
    sc = (a / 3 == 0) ? C13 : C23;
  } else {
    int r = i - 1470; stride = 128; size = 192.0; oh = 4; a = r / 16; pos = r % 16;
    int si = a / 3;
    sc = (si == 0) ? 1.0 : ((si == 1) ? C13 : C23);
  }
  int ari = a % 3;
  double ar = (ari == 0) ? 0.667 : ((ari == 1) ? 1.0 : 1.5);
  int gy = pos / oh, gx = pos % oh;
  float cy = 0.5f * (float)stride + (float)(stride * gy);
  float cx = 0.5f * (float)stride + (float)(stride * gx);
  double ss = sqrt(ar);
  double hd = (size * sc) / ss;
  double wd = (size * sc) * ss;
  float hh = (float)(hd * 0.5), wh = (float)(wd * 0.5);
  float e0 = (cy - hh) + 224.0f;
  float e1 = (cx - wh) + 224.0f;
  float e2 = (cy + hh) + 224.0f;
  float e3 = (cx + wh) + 224.0f;
  int y0 = (int)e0, x0 = (int)e1, y1i = (int)e2, x1i = (int)e3;
  anch[i * 4 + 0] = y0; anch[i * 4 + 1] = x0;
  anch[i * 4 + 2] = y1i; anch[i * 4 + 3] = x1i;
  areas[i] = (float)(y1i - y0) * (float)(x1i - x0);
}

// ---------------- weight permute: wp[o][tap][c] = w[o][c][tap] --------------
__global__ __launch_bounds__(256) void permute_w(const float* __restrict__ w,
                                                 float* __restrict__ wp,
                                                 int Cout, int Cin) {
  int idx = blockIdx.x * 256 + threadIdx.x;
  int total = Cout * 9 * Cin;
  if (idx >= total) return;
  int c = idx % Cin; int t2 = idx / Cin; int tap = t2 % 9; int o = t2 / 9;
  wp[idx] = w[(o * Cin + c) * 9 + tap];
}

// ---------------- f32 -> f16 hi/lo split (linear, scale WSCALE) -------------
__global__ __launch_bounds__(256) void split_w(const float* __restrict__ src,
                                               _Float16* __restrict__ h,
                                               _Float16* __restrict__ l, int n8) {
  int i = blockIdx.x * 256 + threadIdx.x;
  if (i >= n8) return;
  float4 v0 = *(const float4*)(src + (size_t)i * 8);
  float4 v1 = *(const float4*)(src + (size_t)i * 8 + 4);
  float vv[8] = {v0.x, v0.y, v0.z, v0.w, v1.x, v1.y, v1.z, v1.w};
  h8 vh, vl;
#pragma unroll
  for (int j = 0; j < 8; ++j) {
    float s = vv[j] * WSCALE;
    _Float16 a = (_Float16)s;
    vh[j] = a; vl[j] = (_Float16)(s - (float)a);
  }
  *(h8*)(h + (size_t)i * 8) = vh;
  *(h8*)(l + (size_t)i * 8) = vl;
}

// ---------------- x patchify -> A hi/lo [1664][3072] (scale ASCALE) ---------
__global__ __launch_bounds__(256) void split_x(const float* __restrict__ x,
                                               _Float16* __restrict__ Ah,
                                               _Float16* __restrict__ Al) {
  int i = blockIdx.x * 256 + threadIdx.x;
  if (i >= 1664 * 384) return;
  int kq = i % 384, m = i / 384;
  int k = kq * 8;
  h8 vh = {}, vl = {};
  if (m < 1568) {
    int b = m / 196, pos = m % 196;
    int c = k >> 10, r = (k >> 5) & 31, col = k & 31;
    int py = (pos / 14) * 32 + r, px = (pos % 14) * 32 + col;
    const float* sp2 = x + (((size_t)(b * 3 + c) * 448 + py) * 448 + px);
    float4 v0 = *(const float4*)sp2;
    float4 v1 = *(const float4*)(sp2 + 4);
    float vv[8] = {v0.x, v0.y, v0.z, v0.w, v1.x, v1.y, v1.z, v1.w};
#pragma unroll
    for (int j = 0; j < 8; ++j) {
      float s = vv[j] * ASCALE;
      _Float16 a = (_Float16)s;
      vh[j] = a; vl[j] = (_Float16)(s - (float)a);
    }
  }
  *(h8*)(Ah + (size_t)m * 3072 + k) = vh;
  *(h8*)(Al + (size_t)m * 3072 + k) = vl;
}

// ---------------- raw f32 [1568][2048] -> hi/lo [1664][2048] ----------------
__global__ __launch_bounds__(256) void split_raw(const float* __restrict__ raw,
                                                 _Float16* __restrict__ h,
                                                 _Float16* __restrict__ l) {
  int i = blockIdx.x * 256 + threadIdx.x;
  if (i >= 1664 * 256) return;
  int m = i / 256, kq = i % 256;
  int k = kq * 8;
  h8 vh = {}, vl = {};
  if (m < 1568) {
    float4 v0 = *(const float4*)(raw + (size_t)m * 2048 + k);
    float4 v1 = *(const float4*)(raw + (size_t)m * 2048 + k + 4);
    float vv[8] = {v0.x, v0.y, v0.z, v0.w, v1.x, v1.y, v1.z, v1.w};
#pragma unroll
    for (int j = 0; j < 8; ++j) {
      float s = vv[j] * ASCALE;
      _Float16 a = (_Float16)s;
      vh[j] = a; vl[j] = (_Float16)(s - (float)a);
    }
  }
  *(h8*)(h + (size_t)m * 2048 + k) = vh;
  *(h8*)(l + (size_t)m * 2048 + k) = vl;
}

// ---------------- backbone GEMM (MFMA, f16-split 3-product) -----------------
__global__ __launch_bounds__(256) void gemm_bb_mfma(
    const _Float16* __restrict__ Ah, const _Float16* __restrict__ Al,
    const _Float16* __restrict__ Bh, const _Float16* __restrict__ Bl,
    const float* __restrict__ bias, float* __restrict__ C) {
  __shared__ __align__(16) char lds[32768];  // Ah|Al|Bh|Bl tiles, 8KB each
  const int t = threadIdx.x;
  const int m0 = blockIdx.x * 128, n0 = blockIdx.y * 128;
  const int lane = t & 63, w = t >> 6;
  const int wm = (w >> 1) * 64, wn = (w & 1) * 64;
  const int lrow = lane & 15, kg = lane >> 4;

  int offA[4], offB[4];
#pragma unroll
  for (int i = 0; i < 4; ++i) {
    int ba = (wm + i * 16 + lrow) * 64 + kg * 16;
    offA[i] = ba ^ (((ba >> 7) & 3) << 4);
    int bb2 = (wn + i * 16 + lrow) * 64 + kg * 16;
    offB[i] = bb2 ^ (((bb2 >> 7) & 3) << 4);
  }
  size_t gAo[2], gBo[2];
  int ldso[2];
#pragma unroll
  for (int e = 0; e < 2; ++e) {
    int p = e * 256 + t;
    int lsl = p ^ ((p >> 3) & 3);   // inverse swizzle (involution) in slot units
    int row = lsl >> 2, kq = lsl & 3;
    gAo[e] = (size_t)(m0 + row) * 3072 + kq * 8;
    gBo[e] = (size_t)(n0 + row) * 3072 + kq * 8;
    ldso[e] = e * 4096 + (t & 192) * 16;
  }

  f32x4 acc[4][4] = {};
  for (int k0 = 0; k0 < 3072; k0 += 32) {
#pragma unroll
    for (int e = 0; e < 2; ++e) {
      gload16(Ah + gAo[e] + k0, lds + ldso[e]);
      gload16(Al + gAo[e] + k0, lds + 8192 + ldso[e]);
      gload16(Bh + gBo[e] + k0, lds + 16384 + ldso[e]);
      gload16(Bl + gBo[e] + k0, lds + 24576 + ldso[e]);
    }
    __syncthreads();
    h8 fah[4], fal[4], fbh[4], fbl[4];
#pragma unroll
    for (int i = 0; i < 4; ++i) {
      fah[i] = *(const h8*)(lds + offA[i]);
      fal[i] = *(const h8*)(lds + 8192 + offA[i]);
      fbh[i] = *(const h8*)(lds + 16384 + offB[i]);
      fbl[i] = *(const h8*)(lds + 24576 + offB[i]);
    }
#pragma unroll
    for (int i = 0; i < 4; ++i)
#pragma unroll
      for (int j = 0; j < 4; ++j)
        acc[i][j] = __builtin_amdgcn_mfma_f32_16x16x32_f16(fah[i], fbh[j], acc[i][j], 0, 0, 0);
#pragma unroll
    for (int i = 0; i < 4; ++i)
#pragma unroll
      for (int j = 0; j < 4; ++j)
        acc[i][j] = __builtin_amdgcn_mfma_f32_16x16x32_f16(fah[i], fbl[j], acc[i][j], 0, 0, 0);
#pragma unroll
    for (int i = 0; i < 4; ++i)
#pragma unroll
      for (int j = 0; j < 4; ++j)
        acc[i][j] = __builtin_amdgcn_mfma_f32_16x16x32_f16(fal[i], fbh[j], acc[i][j], 0, 0, 0);
    __syncthreads();
  }
  const int prow = (lane >> 4) * 4;
#pragma unroll
  for (int i = 0; i < 4; ++i) {
#pragma unroll
    for (int j = 0; j < 4; ++j) {
      int n = n0 + wn + j * 16 + lrow;
      float bn = bias[n];
#pragma unroll
      for (int r = 0; r < 4; ++r) {
        int m = m0 + wm + i * 16 + prow + r;
        if (m < 1568)
          C[(size_t)m * 2048 + n] = fmaxf(fmaf(acc[i][j][r], RSCALE, bn), 0.f);
      }
    }
  }
}

// ---------------- navigator y1 GEMM (MFMA f16-split, split-K=16) ------------
__global__ __launch_bounds__(256) void gemm_nav_mfma(
    const _Float16* __restrict__ Ah, const _Float16* __restrict__ Al,
    const _Float16* __restrict__ Bh, const _Float16* __restrict__ Bl,
    float* __restrict__ part) {
  __shared__ __align__(16) char lds[32768];
  const int t = threadIdx.x;
  const int m0 = blockIdx.x * 128;
  const int sp = blockIdx.y;  // 0..15
  const int lane = t & 63, w = t >> 6;
  const int wm = (w >> 1) * 64, wn = (w & 1) * 64;
  const int lrow = lane & 15, kg = lane >> 4;

  int offA[4], offB[4];
#pragma unroll
  for (int i = 0; i < 4; ++i) {
    int ba = (wm + i * 16 + lrow) * 64 + kg * 16;
    offA[i] = ba ^ (((ba >> 7) & 3) << 4);
    int bb2 = (wn + i * 16 + lrow) * 64 + kg * 16;
    offB[i] = bb2 ^ (((bb2 >> 7) & 3) << 4);
  }
  size_t gBo[2];
  int ldso[2], akq8[2], ab[2], apy[2], apx[2], amv[2];
#pragma unroll
  for (int e = 0; e < 2; ++e) {
    int p = e * 256 + t;
    int lsl = p ^ ((p >> 3) & 3);
    int row = lsl >> 2, kq = lsl & 3;
    gBo[e] = (size_t)row * 18432 + kq * 8;
    ldso[e] = e * 4096 + (t & 192) * 16;
    int m = m0 + row;
    amv[e] = (m < 1568);
    int b = m / 196, pos = m % 196;
    ab[e] = b; apy[e] = pos / 14; apx[e] = pos % 14;
    akq8[e] = kq * 8;
  }

  f32x4 acc[4][4] = {};
  const int kbeg = sp * 1152, kend = kbeg + 1152;
  for (int k0 = kbeg; k0 < kend; k0 += 32) {
    const int tap = k0 >> 11;
    const int c = k0 & 2047;
    const int dy = tap / 3 - 1, dx = tap % 3 - 1;
#pragma unroll
    for (int e = 0; e < 2; ++e) {
      int sy = apy[e] + dy, sx = apx[e] + dx;
      bool ok = amv[e] && ((unsigned)sy < 14u) && ((unsigned)sx < 14u);
      size_t rowi = ok ? (size_t)(ab[e] * 196 + sy * 14 + sx) : (size_t)1600;
      size_t ao = rowi * 2048 + c + akq8[e];
      gload16(Ah + ao, lds + ldso[e]);
      gload16(Al + ao, lds + 8192 + ldso[e]);
      gload16(Bh + gBo[e] + k0, lds + 16384 + ldso[e]);
      gload16(Bl + gBo[e] + k0, lds + 24576 + ldso[e]);
    }
    __syncthreads();
    h8 fah[4], fal[4], fbh[4], fbl[4];
#pragma unroll
    for (int i = 0; i < 4; ++i) {
      fah[i] = *(const h8*)(lds + offA[i]);
      fal[i] = *(const h8*)(lds + 8192 + offA[i]);
      fbh[i] = *(const h8*)(lds + 16384 + offB[i]);
      fbl[i] = *(const h8*)(lds + 24576 + offB[i]);
    }
#pragma unroll
    for (int i = 0; i < 4; ++i)
#pragma unroll
      for (int j = 0; j < 4; ++j)
        acc[i][j] = __builtin_amdgcn_mfma_f32_16x16x32_f16(fah[i], fbh[j], acc[i][j], 0, 0, 0);
#pragma unroll
    for (int i = 0; i < 4; ++i)
#pragma unroll
      for (int j = 0; j < 4; ++j)
        acc[i][j] = __builtin_amdgcn_mfma_f32_16x16x32_f16(fah[i], fbl[j], acc[i][j], 0, 0, 0);
#pragma unroll
    for (int i = 0; i < 4; ++i)
#pragma unroll
      for (int j = 0; j < 4; ++j)
        acc[i][j] = __builtin_amdgcn_mfma_f32_16x16x32_f16(fal[i], fbh[j], acc[i][j], 0, 0, 0);
    __syncthreads();
  }
  const int prow = (lane >> 4) * 4;
#pragma unroll
  for (int i = 0; i < 4; ++i) {
#pragma unroll
    for (int j = 0; j < 4; ++j) {
      int n = wn + j * 16 + lrow;
#pragma unroll
      for (int r = 0; r < 4; ++r) {
        int m = m0 + wm + i * 16 + prow + r;
        if (m < 1568)
          part[((size_t)sp * 1568 + m) * 128 + n] = acc[i][j][r] * RSCALE;
      }
    }
  }
}

__global__ __launch_bounds__(256) void y1_reduce(const float* __restrict__ part,
                                                 const float* __restrict__ b1,
                                                 float* __restrict__ y1) {
  int idx = blockIdx.x * 256 + threadIdx.x;
  if (idx >= 1568 * 128) return;
  int o = idx & 127;
  float s = b1[o];
#pragma unroll
  for (int sp = 0; sp < 16; ++sp) s += part[(size_t)sp * 1568 * 128 + idx];
  y1[idx] = fmaxf(s, 0.f);
}

// ---------------- small 3x3 stride-2 pad-1 convs (128->128 ch, NHWC) --------
__global__ __launch_bounds__(256) void conv3x3s2(const float* __restrict__ in,
                                                 const float* __restrict__ wp,
                                                 const float* __restrict__ bias,
                                                 float* __restrict__ out,
                                                 int Hin, int Hout) {
  int idx = blockIdx.x * 256 + threadIdx.x;
  int total = 8 * Hout * Hout * 128;
  if (idx >= total) return;
  int o = idx & 127; int pos = idx >> 7;
  int ox = pos % Hout; int t2 = pos / Hout; int oy = t2 % Hout; int b = t2 / Hout;
  float acc = bias[o];
  for (int dy = 0; dy < 3; ++dy) {
    int iy = 2 * oy - 1 + dy;
    if (iy < 0 || iy >= Hin) continue;
    for (int dx = 0; dx < 3; ++dx) {
      int ix = 2 * ox - 1 + dx;
      if (ix < 0 || ix >= Hin) continue;
      const float* ip = in + ((b * Hin + iy) * Hin + ix) * 128;
      const float* wgt = wp + (o * 9 + dy * 3 + dx) * 128;
#pragma unroll 4
      for (int c = 0; c < 128; c += 4) {
        float4 a = *(const float4*)(ip + c);
        float4 ww = *(const float4*)(wgt + c);
        acc += a.x * ww.x + a.y * ww.y + a.z * ww.z + a.w * ww.w;
      }
    }
  }
  out[idx] = fmaxf(acc, 0.f);
}

// ---------------- rpn scores ------------------------------------------------
__global__ __launch_bounds__(256) void scores_kernel(
    const float* __restrict__ y1, const float* __restrict__ y2,
    const float* __restrict__ y3, const float* __restrict__ t1w,
    const float* __restrict__ t1b, const float* __restrict__ t2w,
    const float* __restrict__ t2b, const float* __restrict__ t3w,
    const float* __restrict__ t3b, float* __restrict__ scores) {
  int idx = blockIdx.x * 256 + threadIdx.x;
  if (idx >= 8 * 1614) return;
  int b = idx / 1614, sI = idx % 1614;
  const float* f; const float* w; float bias;
  if (sI < 1176) {
    int a = sI / 196;
    f = y1 + (b * 196 + (sI % 196)) * 128; w = t1w + a * 128; bias = t1b[a];
  } else if (sI < 1470) {
    int r = sI - 1176; int a = r / 49;
    f = y2 + (b * 49 + (r % 49)) * 128; w = t2w + a * 128; bias = t2b[a];
  } else {
    int r = sI - 1470; int a = r / 16;
    f = y3 + (b * 16 + (r % 16)) * 128; w = t3w + a * 128; bias = t3b[a];
  }
  float acc = 0.f;
  for (int c = 0; c < 128; c += 4) {
    float4 a4 = *(const float4*)(f + c);
    float4 w4 = *(const float4*)(w + c);
    acc += a4.x * w4.x + a4.y * w4.y + a4.z * w4.z + a4.w * w4.w;
  }
  scores[idx] = acc + bias;
}

// ---------------- greedy NMS (per batch block) ------------------------------
__global__ __launch_bounds__(256) void nms_kernel(const float* __restrict__ scores,
                                                  const int* __restrict__ anch,
                                                  const float* __restrict__ areas,
                                                  int* __restrict__ boxes) {
  const int b = blockIdx.x, t = threadIdx.x;
  const float* s = scores + b * 1614;
  __shared__ unsigned char valid[1614];
  __shared__ float rv[256];
  __shared__ int ri[256];
  for (int i = t; i < 1614; i += 256) valid[i] = 1;
  __syncthreads();
  for (int n = 0; n < 4; ++n) {
    float best = -INFINITY; int bi = 0x7fffffff;
    for (int i = t; i < 1614; i += 256) {
      if (valid[i]) {
        float v = s[i];
        if (v > best || (v == best && i < bi)) { best = v; bi = i; }
      }
    }
    rv[t] = best; ri[t] = bi;
    __syncthreads();
    for (int off = 128; off > 0; off >>= 1) {
      if (t < off) {
        float ov = rv[t + off]; int oi = ri[t + off];
        if (ov > rv[t] || (ov == rv[t] && oi < ri[t])) { rv[t] = ov; ri[t] = oi; }
      }
      __syncthreads();
    }
    int sel = ri[0];
    if (sel > 1613) sel = 0;
    const int4 bb = ((const int4*)anch)[sel];
    const float Ai = areas[sel];
    if (t == 0) ((int4*)boxes)[b * 4 + n] = bb;
    __syncthreads();
    for (int i = t; i < 1614; i += 256) {
      if (!valid[i]) continue;
      const int4 ab = ((const int4*)anch)[i];
      float sy = fmaxf((float)ab.x, (float)bb.x);
      float sx = fmaxf((float)ab.y, (float)bb.y);
      float ey = fminf((float)ab.z, (float)bb.z);
      float ex = fminf((float)ab.w, (float)bb.w);
      float ly = ey - sy, lx = ex - sx;
      float inter = (ly < 0.f || lx < 0.f) ? 0.f : ly * lx;
      float iou = inter / (areas[i] + Ai - inter);
      if (iou >= 0.25f) valid[i] = 0;
    }
    __syncthreads();
  }
}

// ---------------- bilinear crop -> A hi/lo (im2col layout, scaled) ----------
__global__ __launch_bounds__(256) void crop_kernel(const float* __restrict__ x,
                                                   const int* __restrict__ boxes,
                                                   _Float16* __restrict__ Ah,
                                                   _Float16* __restrict__ Al) {
  int idx = blockIdx.x * 256 + threadIdx.x;
  if (idx >= 32 * 3 * 224 * 224) return;
  int px = idx % 224; int t1 = idx / 224; int py = t1 % 224; int t2 = t1 / 224;
  int c = t2 % 3; int p = t2 / 3;
  int b = p >> 2;
  const int4 bb = ((const int4*)boxes)[p];
  float ty = (float)py / 223.0f;
  float txf = (float)px / 223.0f;
  float ys = (float)bb.x + ty * (float)(bb.z - bb.x - 1);
  float xs = (float)bb.y + txf * (float)(bb.w - bb.y - 1);
  float yf = floorf(ys), xf = floorf(xs);
  float wy = ys - yf, wx = xs - xf;
  int yl = (int)yf, xl = (int)xf;
  int yh = min(yl + 1, 895), xh = min(xl + 1, 895);
  const float* img = x + (size_t)(b * 3 + c) * 448 * 448;
  auto samp = [&](int yy, int xx) -> float {
    yy -= 224; xx -= 224;
    if (yy < 0 || yy >= 448 || xx < 0 || xx >= 448) return 0.f;
    return img[yy * 448 + xx];
  };
  float v00 = samp(yl, xl), v01 = samp(yl, xh);
  float v10 = samp(yh, xl), v11 = samp(yh, xh);
  float top = v00 * (1.f - wx) + v01 * wx;
  float bot = v10 * (1.f - wx) + v11 * wx;
  float val = top * (1.f - wy) + bot * wy;
  int i = py >> 5, r = py & 31, j = px >> 5, col = px & 31;
  int m = p * 49 + i * 7 + j;
  int k = (c << 10) + (r << 5) + col;
  float s = val * ASCALE;
  _Float16 a = (_Float16)s;
  Ah[(size_t)m * 3072 + k] = a;
  Al[(size_t)m * 3072 + k] = (_Float16)(s - (float)a);
}

// ---------------- parallel spatial mean -------------------------------------
// grid.x = groups * 8; block handles one group x 256 consecutive columns.
__global__ __launch_bounds__(256) void mean_kernel(const float* __restrict__ in,
                                                   float* __restrict__ out,
                                                   int rows) {
  int g = blockIdx.x >> 3;
  int o = ((blockIdx.x & 7) << 8) + threadIdx.x;
  const float* base = in + ((size_t)g * rows) * 2048 + o;
  float s0 = 0.f, s1 = 0.f, s2 = 0.f, s3 = 0.f;
  int r = 0;
  for (; r + 4 <= rows; r += 4) {
    s0 += base[(size_t)(r + 0) * 2048];
    s1 += base[(size_t)(r + 1) * 2048];
    s2 += base[(size_t)(r + 2) * 2048];
    s3 += base[(size_t)(r + 3) * 2048];
  }
  for (; r < rows; ++r) s0 += base[(size_t)r * 2048];
  out[(size_t)g * 2048 + o] = ((s0 + s1) + (s2 + s3)) / (float)rows;
}

// ---------------- final linear: one wave per (b, class) ---------------------
__global__ __launch_bounds__(256) void final_kernel(const float* __restrict__ pfeat,
                                                    const float* __restrict__ rfeat,
                                                    const float* __restrict__ cw,
                                                    const float* __restrict__ cb,
                                                    float* __restrict__ out) {
  int gw = (blockIdx.x * 256 + threadIdx.x) >> 6;
  int lane = threadIdx.x & 63;
  if (gw >= 1600) return;
  int b = gw / 200, j = gw % 200;
  const float* wr = cw + (size_t)j * 10240;
  const float* pf = pfeat + (size_t)b * 8192;
  float acc = 0.f;
  for (int k = lane * 4; k < 8192; k += 256) {
    float4 a = *(const float4*)(pf + k);
    float4 w = *(const float4*)(wr + k);
    acc += a.x * w.x + a.y * w.y + a.z * w.z + a.w * w.w;
  }
  const float* rf = rfeat + (size_t)b * 2048;
  const float* wr2 = wr + 8192;
  for (int k = lane * 4; k < 2048; k += 256) {
    float4 a = *(const float4*)(rf + k);
    float4 w = *(const float4*)(wr2 + k);
    acc += a.x * w.x + a.y * w.y + a.z * w.z + a.w * w.w;
  }
#pragma unroll
  for (int off = 32; off > 0; off >>= 1) acc += __shfl_down(acc, off, 64);
  if (lane == 0) out[b * 200 + j] = acc + cb[j];
}

// ---------------------------------------------------------------------------
extern "C" void kernel_launch(void* const* d_in, const int* in_sizes, int n_in,
                              void* d_out, int out_size, void* d_ws, size_t ws_size,
                              hipStream_t stream) {
  const float* x   = (const float*)d_in[0];
  const float* bbw = (const float*)d_in[1];
  const float* bbb = (const float*)d_in[2];
  const float* w1  = (const float*)d_in[3];
  const float* b1  = (const float*)d_in[4];
  const float* t1w = (const float*)d_in[5];
  const float* t1b = (const float*)d_in[6];
  const float* w2  = (const float*)d_in[7];
  const float* b2  = (const float*)d_in[8];
  const float* t2w = (const float*)d_in[9];
  const float* t2b = (const float*)d_in[10];
  const float* w3  = (const float*)d_in[11];
  const float* b3  = (const float*)d_in[12];
  const float* t3w = (const float*)d_in[13];
  const float* t3b = (const float*)d_in[14];
  const float* cw  = (const float*)d_in[15];
  const float* cb  = (const float*)d_in[16];
  float* out = (float*)d_out;

  char* p = (char*)d_ws;
  auto alloc = [&](size_t bytes) -> char* {
    char* r = p; p += (bytes + 255) & ~(size_t)255; return r;
  };
  int*      anch  = (int*)     alloc((size_t)1614 * 4 * 4);
  float*    areas = (float*)   alloc((size_t)1614 * 4);
  float*    w1p   = (float*)   alloc((size_t)128 * 18432 * 4);
  _Float16* bWh   = (_Float16*)alloc((size_t)2048 * 3072 * 2);
  _Float16* bWl   = (_Float16*)alloc((size_t)2048 * 3072 * 2);
  _Float16* w1h   = (_Float16*)alloc((size_t)128 * 18432 * 2);
  _Float16* w1l   = (_Float16*)alloc((size_t)128 * 18432 * 2);
  _Float16* Ahh   = (_Float16*)alloc((size_t)1664 * 3072 * 2);
  _Float16* All   = (_Float16*)alloc((size_t)1664 * 3072 * 2);
  _Float16* rawh  = (_Float16*)alloc((size_t)1664 * 2048 * 2);
  _Float16* rawl  = (_Float16*)alloc((size_t)1664 * 2048 * 2);
  float*    raw   = (float*)   alloc((size_t)1568 * 2048 * 4);
  float*    w2p   = (float*)   alloc((size_t)128 * 9 * 128 * 4);
  float*    w3p   = (float*)   alloc((size_t)128 * 9 * 128 * 4);
  float*    y1s   = (float*)   alloc((size_t)16 * 1568 * 128 * 4);
  float*    y1v   = (float*)   alloc((size_t)1568 * 128 * 4);
  float*    y2v   = (float*)   alloc((size_t)392 * 128 * 4);
  float*    y3v   = (float*)   alloc((size_t)128 * 128 * 4);
  float*    sc    = (float*)   alloc((size_t)8 * 1614 * 4);
  int*      boxes = (int*)     alloc((size_t)8 * 4 * 4 * 4);
  float*    pfeat = (float*)   alloc((size_t)32 * 2048 * 4);
  float*    rfeat = (float*)   alloc((size_t)8 * 2048 * 4);

  anchors_kernel<<<7, 256, 0, stream>>>(anch, areas);
  permute_w<<<(128 * 9 * 2048 + 255) / 256, 256, 0, stream>>>(w1, w1p, 128, 2048);
  permute_w<<<(128 * 9 * 128 + 255) / 256, 256, 0, stream>>>(w2, w2p, 128, 128);
  permute_w<<<(128 * 9 * 128 + 255) / 256, 256, 0, stream>>>(w3, w3p, 128, 128);
  split_w<<<(2048 * 3072 / 8 + 255) / 256, 256, 0, stream>>>(bbw, bWh, bWl, 2048 * 3072 / 8);
  split_w<<<(128 * 18432 / 8 + 255) / 256, 256, 0, stream>>>(w1p, w1h, w1l, 128 * 18432 / 8);
  split_x<<<(1664 * 384 + 255) / 256, 256, 0, stream>>>(x, Ahh, All);

  gemm_bb_mfma<<<dim3(13, 16), 256, 0, stream>>>(Ahh, All, bWh, bWl, bbb, raw);
  split_raw<<<(1664 * 256 + 255) / 256, 256, 0, stream>>>(raw, rawh, rawl);
  gemm_nav_mfma<<<dim3(13, 16), 256, 0, stream>>>(rawh, rawl, w1h, w1l, y1s);
  y1_reduce<<<(1568 * 128 + 255) / 256, 256, 0, stream>>>(y1s, b1, y1v);
  mean_kernel<<<64, 256, 0, stream>>>(raw, rfeat, 196);
  conv3x3s2<<<(8 * 7 * 7 * 128 + 255) / 256, 256, 0, stream>>>(y1v, w2p, b2, y2v, 14, 7);
  conv3x3s2<<<(8 * 4 * 4 * 128 + 255) / 256, 256, 0, stream>>>(y2v, w3p, b3, y3v, 7, 4);
  scores_kernel<<<(8 * 1614 + 255) / 256, 256, 0, stream>>>(
      y1v, y2v, y3v, t1w, t1b, t2w, t2b, t3w, t3b, sc);
  nms_kernel<<<8, 256, 0, stream>>>(sc, anch, areas, boxes);
  crop_kernel<<<(32 * 3 * 224 * 224) / 256, 256, 0, stream>>>(x, boxes, Ahh, All);
  gemm_bb_mfma<<<dim3(13, 16), 256, 0, stream>>>(Ahh, All, bWh, bWl, bbb, raw);
  mean_kernel<<<256, 256, 0, stream>>>(raw, pfeat, 49);
  final_kernel<<<400, 256, 0, stream>>>(pfeat, rfeat, cw, cb, out);
}

// Round 4
// 415.683 us; speedup vs baseline: 3.9435x; 1.2116x over previous
//
#include <hip/hip_runtime.h>
#include <math.h>

// ---------------------------------------------------------------------------
// NTSNet forward. Big GEMMs on MFMA via 2-way f16 split (3 products: hh,hl,lh)
// R2: parallel mean kernels. R3: split-K GEMMs for >=2 blocks/CU occupancy
//     (was 208 blocks on 256 CUs -> latency-bound, MfmaUtil 19%).
// ---------------------------------------------------------------------------

typedef _Float16 h8 __attribute__((ext_vector_type(8)));
typedef float f32x4 __attribute__((ext_vector_type(4)));

#define ASCALE 256.0f
#define WSCALE 16384.0f
#define RSCALE (1.0f / (256.0f * 16384.0f))

__device__ __forceinline__ void gload16(const void* g, void* l) {
  __builtin_amdgcn_global_load_lds(
      (__attribute__((address_space(1))) void*)(void*)(uintptr_t)g,
      (__attribute__((address_space(3))) void*)l, 16, 0, 0);
}

// ---------------- anchors (faithful port of _generate_default_anchor_maps) --
__global__ __launch_bounds__(256) void anchors_kernel(int* __restrict__ anch,
                                                      float* __restrict__ areas) {
  int i = blockIdx.x * 256 + threadIdx.x;
  if (i >= 1614) return;
  int stride, oh, a, pos;
  double size, sc;
  const double C13 = 1.2599210498948732;
  const double C23 = 1.5874010519681994;
  if (i < 1176) {
    stride = 32; size = 48.0; oh = 14; a = i / 196; pos = i % 196;
    sc = (a / 3 == 0) ? C13 : C23;
  } else if (i < 1470) {
    int r = i - 1176; stride = 64; size = 96.0; oh = 7; a = r / 49; pos = r % 49;
    sc = (a / 3 == 0) ? C13 : C23;
  } else {
    int r = i - 1470; stride = 128; size = 192.0; oh = 4; a = r / 16; pos = r % 16;
    int si = a / 3;
    sc = (si == 0) ? 1.0 : ((si == 1) ? C13 : C23);
  }
  int ari = a % 3;
  double ar = (ari == 0) ? 0.667 : ((ari == 1) ? 1.0 : 1.5);
  int gy = pos / oh, gx = pos % oh;
  float cy = 0.5f * (float)stride + (float)(stride * gy);
  float cx = 0.5f * (float)stride + (float)(stride * gx);
  double ss = sqrt(ar);
  double hd = (size * sc) / ss;
  double wd = (size * sc) * ss;
  float hh = (float)(hd * 0.5), wh = (float)(wd * 0.5);
  float e0 = (cy - hh) + 224.0f;
  float e1 = (cx - wh) + 224.0f;
  float e2 = (cy + hh) + 224.0f;
  float e3 = (cx + wh) + 224.0f;
  int y0 = (int)e0, x0 = (int)e1, y1i = (int)e2, x1i = (int)e3;
  anch[i * 4 + 0] = y0; anch[i * 4 + 1] = x0;
  anch[i * 4 + 2] = y1i; anch[i * 4 + 3] = x1i;
  areas[i] = (float)(y1i - y0) * (float)(x1i - x0);
}

// ---------------- weight permute: wp[o][tap][c] = w[o][c][tap] --------------
__global__ __launch_bounds__(256) void permute_w(const float* __restrict__ w,
                                                 float* __restrict__ wp,
                                                 int Cout, int Cin) {
  int idx = blockIdx.x * 256 + threadIdx.x;
  int total = Cout * 9 * Cin;
  if (idx >= total) return;
  int c = idx % Cin; int t2 = idx / Cin; int tap = t2 % 9; int o = t2 / 9;
  wp[idx] = w[(o * Cin + c) * 9 + tap];
}

// ---------------- f32 -> f16 hi/lo split (linear, scale WSCALE) -------------
__global__ __launch_bounds__(256) void split_w(const float* __restrict__ src,
                                               _Float16* __restrict__ h,
                                               _Float16* __restrict__ l, int n8) {
  int i = blockIdx.x * 256 + threadIdx.x;
  if (i >= n8) return;
  float4 v0 = *(const float4*)(src + (size_t)i * 8);
  float4 v1 = *(const float4*)(src + (size_t)i * 8 + 4);
  float vv[8] = {v0.x, v0.y, v0.z, v0.w, v1.x, v1.y, v1.z, v1.w};
  h8 vh, vl;
#pragma unroll
  for (int j = 0; j < 8; ++j) {
    float s = vv[j] * WSCALE;
    _Float16 a = (_Float16)s;
    vh[j] = a; vl[j] = (_Float16)(s - (float)a);
  }
  *(h8*)(h + (size_t)i * 8) = vh;
  *(h8*)(l + (size_t)i * 8) = vl;
}

// ---------------- x patchify -> A hi/lo [1664][3072] (scale ASCALE) ---------
__global__ __launch_bounds__(256) void split_x(const float* __restrict__ x,
                                               _Float16* __restrict__ Ah,
                                               _Float16* __restrict__ Al) {
  int i = blockIdx.x * 256 + threadIdx.x;
  if (i >= 1664 * 384) return;
  int kq = i % 384, m = i / 384;
  int k = kq * 8;
  h8 vh = {}, vl = {};
  if (m < 1568) {
    int b = m / 196, pos = m % 196;
    int c = k >> 10, r = (k >> 5) & 31, col = k & 31;
    int py = (pos / 14) * 32 + r, px = (pos % 14) * 32 + col;
    const float* sp2 = x + (((size_t)(b * 3 + c) * 448 + py) * 448 + px);
    float4 v0 = *(const float4*)sp2;
    float4 v1 = *(const float4*)(sp2 + 4);
    float vv[8] = {v0.x, v0.y, v0.z, v0.w, v1.x, v1.y, v1.z, v1.w};
#pragma unroll
    for (int j = 0; j < 8; ++j) {
      float s = vv[j] * ASCALE;
      _Float16 a = (_Float16)s;
      vh[j] = a; vl[j] = (_Float16)(s - (float)a);
    }
  }
  *(h8*)(Ah + (size_t)m * 3072 + k) = vh;
  *(h8*)(Al + (size_t)m * 3072 + k) = vl;
}

// ---------------- backbone GEMM (MFMA, f16-split 3-product, split-K=2) ------
// Writes raw f32 dot-product partials P[z][1664][2048] (no scale/bias).
__global__ __launch_bounds__(256) void gemm_bb_mfma(
    const _Float16* __restrict__ Ah, const _Float16* __restrict__ Al,
    const _Float16* __restrict__ Bh, const _Float16* __restrict__ Bl,
    float* __restrict__ P) {
  __shared__ __align__(16) char lds[32768];  // Ah|Al|Bh|Bl tiles, 8KB each
  const int t = threadIdx.x;
  const int m0 = blockIdx.x * 128, n0 = blockIdx.y * 128;
  const int kz = blockIdx.z;
  const int lane = t & 63, w = t >> 6;
  const int wm = (w >> 1) * 64, wn = (w & 1) * 64;
  const int lrow = lane & 15, kg = lane >> 4;

  int offA[4], offB[4];
#pragma unroll
  for (int i = 0; i < 4; ++i) {
    int ba = (wm + i * 16 + lrow) * 64 + kg * 16;
    offA[i] = ba ^ (((ba >> 7) & 3) << 4);
    int bb2 = (wn + i * 16 + lrow) * 64 + kg * 16;
    offB[i] = bb2 ^ (((bb2 >> 7) & 3) << 4);
  }
  size_t gAo[2], gBo[2];
  int ldso[2];
#pragma unroll
  for (int e = 0; e < 2; ++e) {
    int p = e * 256 + t;
    int lsl = p ^ ((p >> 3) & 3);   // inverse swizzle (involution) in slot units
    int row = lsl >> 2, kq = lsl & 3;
    gAo[e] = (size_t)(m0 + row) * 3072 + kq * 8;
    gBo[e] = (size_t)(n0 + row) * 3072 + kq * 8;
    ldso[e] = e * 4096 + (t & 192) * 16;
  }

  f32x4 acc[4][4] = {};
  const int kbeg = kz * 1536, kend = kbeg + 1536;
  for (int k0 = kbeg; k0 < kend; k0 += 32) {
#pragma unroll
    for (int e = 0; e < 2; ++e) {
      gload16(Ah + gAo[e] + k0, lds + ldso[e]);
      gload16(Al + gAo[e] + k0, lds + 8192 + ldso[e]);
      gload16(Bh + gBo[e] + k0, lds + 16384 + ldso[e]);
      gload16(Bl + gBo[e] + k0, lds + 24576 + ldso[e]);
    }
    __syncthreads();
    h8 fah[4], fal[4], fbh[4], fbl[4];
#pragma unroll
    for (int i = 0; i < 4; ++i) {
      fah[i] = *(const h8*)(lds + offA[i]);
      fal[i] = *(const h8*)(lds + 8192 + offA[i]);
      fbh[i] = *(const h8*)(lds + 16384 + offB[i]);
      fbl[i] = *(const h8*)(lds + 24576 + offB[i]);
    }
#pragma unroll
    for (int i = 0; i < 4; ++i)
#pragma unroll
      for (int j = 0; j < 4; ++j)
        acc[i][j] = __builtin_amdgcn_mfma_f32_16x16x32_f16(fah[i], fbh[j], acc[i][j], 0, 0, 0);
#pragma unroll
    for (int i = 0; i < 4; ++i)
#pragma unroll
      for (int j = 0; j < 4; ++j)
        acc[i][j] = __builtin_amdgcn_mfma_f32_16x16x32_f16(fah[i], fbl[j], acc[i][j], 0, 0, 0);
#pragma unroll
    for (int i = 0; i < 4; ++i)
#pragma unroll
      for (int j = 0; j < 4; ++j)
        acc[i][j] = __builtin_amdgcn_mfma_f32_16x16x32_f16(fal[i], fbh[j], acc[i][j], 0, 0, 0);
    __syncthreads();
  }
  float* Pz = P + (size_t)kz * 1664 * 2048;
  const int prow = (lane >> 4) * 4;
#pragma unroll
  for (int i = 0; i < 4; ++i) {
#pragma unroll
    for (int j = 0; j < 4; ++j) {
      int n = n0 + wn + j * 16 + lrow;
#pragma unroll
      for (int r = 0; r < 4; ++r) {
        int m = m0 + wm + i * 16 + prow + r;
        Pz[(size_t)m * 2048 + n] = acc[i][j][r];
      }
    }
  }
}

// ---------------- split-K reduce: C = relu((p0+p1)*RSCALE + bias) -----------
// WRITE_SPLIT: also emit h/l f16 split (ASCALE) incl. zeroed rows 1568..1663.
template <int WRITE_SPLIT>
__global__ __launch_bounds__(256) void bb_reduce(const float* __restrict__ P,
                                                 const float* __restrict__ bias,
                                                 float* __restrict__ raw,
                                                 _Float16* __restrict__ h,
                                                 _Float16* __restrict__ l) {
  int idx = blockIdx.x * 256 + threadIdx.x;
  int m = idx >> 8, col = (idx & 255) * 8;
  if (WRITE_SPLIT) {
    if (m >= 1664) return;
    if (m >= 1568) {
      h8 z = {};
      *(h8*)(h + (size_t)m * 2048 + col) = z;
      *(h8*)(l + (size_t)m * 2048 + col) = z;
      return;
    }
  } else {
    if (m >= 1568) return;
  }
  size_t o = (size_t)m * 2048 + col;
  const float* p0 = P + o;
  const float* p1 = P + (size_t)1664 * 2048 + o;
  float4 a0 = *(const float4*)(p0);
  float4 a1 = *(const float4*)(p0 + 4);
  float4 c0 = *(const float4*)(p1);
  float4 c1 = *(const float4*)(p1 + 4);
  float4 b0 = *(const float4*)(bias + col);
  float4 b1 = *(const float4*)(bias + col + 4);
  float v[8];
  v[0] = fmaxf(fmaf(a0.x + c0.x, RSCALE, b0.x), 0.f);
  v[1] = fmaxf(fmaf(a0.y + c0.y, RSCALE, b0.y), 0.f);
  v[2] = fmaxf(fmaf(a0.z + c0.z, RSCALE, b0.z), 0.f);
  v[3] = fmaxf(fmaf(a0.w + c0.w, RSCALE, b0.w), 0.f);
  v[4] = fmaxf(fmaf(a1.x + c1.x, RSCALE, b1.x), 0.f);
  v[5] = fmaxf(fmaf(a1.y + c1.y, RSCALE, b1.y), 0.f);
  v[6] = fmaxf(fmaf(a1.z + c1.z, RSCALE, b1.z), 0.f);
  v[7] = fmaxf(fmaf(a1.w + c1.w, RSCALE, b1.w), 0.f);
  *(float4*)(raw + o) = make_float4(v[0], v[1], v[2], v[3]);
  *(float4*)(raw + o + 4) = make_float4(v[4], v[5], v[6], v[7]);
  if (WRITE_SPLIT) {
    h8 vh, vl;
#pragma unroll
    for (int j = 0; j < 8; ++j) {
      float s = v[j] * ASCALE;
      _Float16 a = (_Float16)s;
      vh[j] = a; vl[j] = (_Float16)(s - (float)a);
    }
    *(h8*)(h + o) = vh;
    *(h8*)(l + o) = vl;
  }
}

// ---------------- navigator y1 GEMM (MFMA f16-split, split-K=32) ------------
__global__ __launch_bounds__(256) void gemm_nav_mfma(
    const _Float16* __restrict__ Ah, const _Float16* __restrict__ Al,
    const _Float16* __restrict__ Bh, const _Float16* __restrict__ Bl,
    float* __restrict__ part) {
  __shared__ __align__(16) char lds[32768];
  const int t = threadIdx.x;
  const int m0 = blockIdx.x * 128;
  const int sp = blockIdx.y;  // 0..31
  const int lane = t & 63, w = t >> 6;
  const int wm = (w >> 1) * 64, wn = (w & 1) * 64;
  const int lrow = lane & 15, kg = lane >> 4;

  int offA[4], offB[4];
#pragma unroll
  for (int i = 0; i < 4; ++i) {
    int ba = (wm + i * 16 + lrow) * 64 + kg * 16;
    offA[i] = ba ^ (((ba >> 7) & 3) << 4);
    int bb2 = (wn + i * 16 + lrow) * 64 + kg * 16;
    offB[i] = bb2 ^ (((bb2 >> 7) & 3) << 4);
  }
  size_t gBo[2];
  int ldso[2], akq8[2], ab[2], apy[2], apx[2], amv[2];
#pragma unroll
  for (int e = 0; e < 2; ++e) {
    int p = e * 256 + t;
    int lsl = p ^ ((p >> 3) & 3);
    int row = lsl >> 2, kq = lsl & 3;
    gBo[e] = (size_t)row * 18432 + kq * 8;
    ldso[e] = e * 4096 + (t & 192) * 16;
    int m = m0 + row;
    amv[e] = (m < 1568);
    int b = m / 196, pos = m % 196;
    ab[e] = b; apy[e] = pos / 14; apx[e] = pos % 14;
    akq8[e] = kq * 8;
  }

  f32x4 acc[4][4] = {};
  const int kbeg = sp * 576, kend = kbeg + 576;
  for (int k0 = kbeg; k0 < kend; k0 += 32) {
    const int tap = k0 >> 11;
    const int c = k0 & 2047;
    const int dy = tap / 3 - 1, dx = tap % 3 - 1;
#pragma unroll
    for (int e = 0; e < 2; ++e) {
      int sy = apy[e] + dy, sx = apx[e] + dx;
      bool ok = amv[e] && ((unsigned)sy < 14u) && ((unsigned)sx < 14u);
      size_t rowi = ok ? (size_t)(ab[e] * 196 + sy * 14 + sx) : (size_t)1600;
      size_t ao = rowi * 2048 + c + akq8[e];
      gload16(Ah + ao, lds + ldso[e]);
      gload16(Al + ao, lds + 8192 + ldso[e]);
      gload16(Bh + gBo[e] + k0, lds + 16384 + ldso[e]);
      gload16(Bl + gBo[e] + k0, lds + 24576 + ldso[e]);
    }
    __syncthreads();
    h8 fah[4], fal[4], fbh[4], fbl[4];
#pragma unroll
    for (int i = 0; i < 4; ++i) {
      fah[i] = *(const h8*)(lds + offA[i]);
      fal[i] = *(const h8*)(lds + 8192 + offA[i]);
      fbh[i] = *(const h8*)(lds + 16384 + offB[i]);
      fbl[i] = *(const h8*)(lds + 24576 + offB[i]);
    }
#pragma unroll
    for (int i = 0; i < 4; ++i)
#pragma unroll
      for (int j = 0; j < 4; ++j)
        acc[i][j] = __builtin_amdgcn_mfma_f32_16x16x32_f16(fah[i], fbh[j], acc[i][j], 0, 0, 0);
#pragma unroll
    for (int i = 0; i < 4; ++i)
#pragma unroll
      for (int j = 0; j < 4; ++j)
        acc[i][j] = __builtin_amdgcn_mfma_f32_16x16x32_f16(fah[i], fbl[j], acc[i][j], 0, 0, 0);
#pragma unroll
    for (int i = 0; i < 4; ++i)
#pragma unroll
      for (int j = 0; j < 4; ++j)
        acc[i][j] = __builtin_amdgcn_mfma_f32_16x16x32_f16(fal[i], fbh[j], acc[i][j], 0, 0, 0);
    __syncthreads();
  }
  const int prow = (lane >> 4) * 4;
#pragma unroll
  for (int i = 0; i < 4; ++i) {
#pragma unroll
    for (int j = 0; j < 4; ++j) {
      int n = wn + j * 16 + lrow;
#pragma unroll
      for (int r = 0; r < 4; ++r) {
        int m = m0 + wm + i * 16 + prow + r;
        if (m < 1568)
          part[((size_t)sp * 1568 + m) * 128 + n] = acc[i][j][r] * RSCALE;
      }
    }
  }
}

__global__ __launch_bounds__(256) void y1_reduce(const float* __restrict__ part,
                                                 const float* __restrict__ b1,
                                                 float* __restrict__ y1) {
  int idx = blockIdx.x * 256 + threadIdx.x;
  if (idx >= 1568 * 128) return;
  int o = idx & 127;
  float s = b1[o];
#pragma unroll
  for (int sp = 0; sp < 32; ++sp) s += part[(size_t)sp * 1568 * 128 + idx];
  y1[idx] = fmaxf(s, 0.f);
}

// ---------------- small 3x3 stride-2 pad-1 convs (128->128 ch, NHWC) --------
__global__ __launch_bounds__(256) void conv3x3s2(const float* __restrict__ in,
                                                 const float* __restrict__ wp,
                                                 const float* __restrict__ bias,
                                                 float* __restrict__ out,
                                                 int Hin, int Hout) {
  int idx = blockIdx.x * 256 + threadIdx.x;
  int total = 8 * Hout * Hout * 128;
  if (idx >= total) return;
  int o = idx & 127; int pos = idx >> 7;
  int ox = pos % Hout; int t2 = pos / Hout; int oy = t2 % Hout; int b = t2 / Hout;
  float acc = bias[o];
  for (int dy = 0; dy < 3; ++dy) {
    int iy = 2 * oy - 1 + dy;
    if (iy < 0 || iy >= Hin) continue;
    for (int dx = 0; dx < 3; ++dx) {
      int ix = 2 * ox - 1 + dx;
      if (ix < 0 || ix >= Hin) continue;
      const float* ip = in + ((b * Hin + iy) * Hin + ix) * 128;
      const float* wgt = wp + (o * 9 + dy * 3 + dx) * 128;
#pragma unroll 4
      for (int c = 0; c < 128; c += 4) {
        float4 a = *(const float4*)(ip + c);
        float4 ww = *(const float4*)(wgt + c);
        acc += a.x * ww.x + a.y * ww.y + a.z * ww.z + a.w * ww.w;
      }
    }
  }
  out[idx] = fmaxf(acc, 0.f);
}

// ---------------- rpn scores ------------------------------------------------
__global__ __launch_bounds__(256) void scores_kernel(
    const float* __restrict__ y1, const float* __restrict__ y2,
    const float* __restrict__ y3, const float* __restrict__ t1w,
    const float* __restrict__ t1b, const float* __restrict__ t2w,
    const float* __restrict__ t2b, const float* __restrict__ t3w,
    const float* __restrict__ t3b, float* __restrict__ scores) {
  int idx = blockIdx.x * 256 + threadIdx.x;
  if (idx >= 8 * 1614) return;
  int b = idx / 1614, sI = idx % 1614;
  const float* f; const float* w; float bias;
  if (sI < 1176) {
    int a = sI / 196;
    f = y1 + (b * 196 + (sI % 196)) * 128; w = t1w + a * 128; bias = t1b[a];
  } else if (sI < 1470) {
    int r = sI - 1176; int a = r / 49;
    f = y2 + (b * 49 + (r % 49)) * 128; w = t2w + a * 128; bias = t2b[a];
  } else {
    int r = sI - 1470; int a = r / 16;
    f = y3 + (b * 16 + (r % 16)) * 128; w = t3w + a * 128; bias = t3b[a];
  }
  float acc = 0.f;
  for (int c = 0; c < 128; c += 4) {
    float4 a4 = *(const float4*)(f + c);
    float4 w4 = *(const float4*)(w + c);
    acc += a4.x * w4.x + a4.y * w4.y + a4.z * w4.z + a4.w * w4.w;
  }
  scores[idx] = acc + bias;
}

// ---------------- greedy NMS (per batch block) ------------------------------
__global__ __launch_bounds__(256) void nms_kernel(const float* __restrict__ scores,
                                                  const int* __restrict__ anch,
                                                  const float* __restrict__ areas,
                                                  int* __restrict__ boxes) {
  const int b = blockIdx.x, t = threadIdx.x;
  const float* s = scores + b * 1614;
  __shared__ unsigned char valid[1614];
  __shared__ float rv[256];
  __shared__ int ri[256];
  for (int i = t; i < 1614; i += 256) valid[i] = 1;
  __syncthreads();
  for (int n = 0; n < 4; ++n) {
    float best = -INFINITY; int bi = 0x7fffffff;
    for (int i = t; i < 1614; i += 256) {
      if (valid[i]) {
        float v = s[i];
        if (v > best || (v == best && i < bi)) { best = v; bi = i; }
      }
    }
    rv[t] = best; ri[t] = bi;
    __syncthreads();
    for (int off = 128; off > 0; off >>= 1) {
      if (t < off) {
        float ov = rv[t + off]; int oi = ri[t + off];
        if (ov > rv[t] || (ov == rv[t] && oi < ri[t])) { rv[t] = ov; ri[t] = oi; }
      }
      __syncthreads();
    }
    int sel = ri[0];
    if (sel > 1613) sel = 0;
    const int4 bb = ((const int4*)anch)[sel];
    const float Ai = areas[sel];
    if (t == 0) ((int4*)boxes)[b * 4 + n] = bb;
    __syncthreads();
    for (int i = t; i < 1614; i += 256) {
      if (!valid[i]) continue;
      const int4 ab = ((const int4*)anch)[i];
      float sy = fmaxf((float)ab.x, (float)bb.x);
      float sx = fmaxf((float)ab.y, (float)bb.y);
      float ey = fminf((float)ab.z, (float)bb.z);
      float ex = fminf((float)ab.w, (float)bb.w);
      float ly = ey - sy, lx = ex - sx;
      float inter = (ly < 0.f || lx < 0.f) ? 0.f : ly * lx;
      float iou = inter / (areas[i] + Ai - inter);
      if (iou >= 0.25f) valid[i] = 0;
    }
    __syncthreads();
  }
}

// ---------------- bilinear crop -> A hi/lo (im2col layout, scaled) ----------
__global__ __launch_bounds__(256) void crop_kernel(const float* __restrict__ x,
                                                   const int* __restrict__ boxes,
                                                   _Float16* __restrict__ Ah,
                                                   _Float16* __restrict__ Al) {
  int idx = blockIdx.x * 256 + threadIdx.x;
  if (idx >= 32 * 3 * 224 * 224) return;
  int px = idx % 224; int t1 = idx / 224; int py = t1 % 224; int t2 = t1 / 224;
  int c = t2 % 3; int p = t2 / 3;
  int b = p >> 2;
  const int4 bb = ((const int4*)boxes)[p];
  float ty = (float)py / 223.0f;
  float txf = (float)px / 223.0f;
  float ys = (float)bb.x + ty * (float)(bb.z - bb.x - 1);
  float xs = (float)bb.y + txf * (float)(bb.w - bb.y - 1);
  float yf = floorf(ys), xf = floorf(xs);
  float wy = ys - yf, wx = xs - xf;
  int yl = (int)yf, xl = (int)xf;
  int yh = min(yl + 1, 895), xh = min(xl + 1, 895);
  const float* img = x + (size_t)(b * 3 + c) * 448 * 448;
  auto samp = [&](int yy, int xx) -> float {
    yy -= 224; xx -= 224;
    if (yy < 0 || yy >= 448 || xx < 0 || xx >= 448) return 0.f;
    return img[yy * 448 + xx];
  };
  float v00 = samp(yl, xl), v01 = samp(yl, xh);
  float v10 = samp(yh, xl), v11 = samp(yh, xh);
  float top = v00 * (1.f - wx) + v01 * wx;
  float bot = v10 * (1.f - wx) + v11 * wx;
  float val = top * (1.f - wy) + bot * wy;
  int i = py >> 5, r = py & 31, j = px >> 5, col = px & 31;
  int m = p * 49 + i * 7 + j;
  int k = (c << 10) + (r << 5) + col;
  float s = val * ASCALE;
  _Float16 a = (_Float16)s;
  Ah[(size_t)m * 3072 + k] = a;
  Al[(size_t)m * 3072 + k] = (_Float16)(s - (float)a);
}

// ---------------- parallel spatial mean -------------------------------------
// grid.x = groups * 8; block handles one group x 256 consecutive columns.
__global__ __launch_bounds__(256) void mean_kernel(const float* __restrict__ in,
                                                   float* __restrict__ out,
                                                   int rows) {
  int g = blockIdx.x >> 3;
  int o = ((blockIdx.x & 7) << 8) + threadIdx.x;
  const float* base = in + ((size_t)g * rows) * 2048 + o;
  float s0 = 0.f, s1 = 0.f, s2 = 0.f, s3 = 0.f;
  int r = 0;
  for (; r + 4 <= rows; r += 4) {
    s0 += base[(size_t)(r + 0) * 2048];
    s1 += base[(size_t)(r + 1) * 2048];
    s2 += base[(size_t)(r + 2) * 2048];
    s3 += base[(size_t)(r + 3) * 2048];
  }
  for (; r < rows; ++r) s0 += base[(size_t)r * 2048];
  out[(size_t)g * 2048 + o] = ((s0 + s1) + (s2 + s3)) / (float)rows;
}

// ---------------- final linear: one wave per (b, class) ---------------------
__global__ __launch_bounds__(256) void final_kernel(const float* __restrict__ pfeat,
                                                    const float* __restrict__ rfeat,
                                                    const float* __restrict__ cw,
                                                    const float* __restrict__ cb,
                                                    float* __restrict__ out) {
  int gw = (blockIdx.x * 256 + threadIdx.x) >> 6;
  int lane = threadIdx.x & 63;
  if (gw >= 1600) return;
  int b = gw / 200, j = gw % 200;
  const float* wr = cw + (size_t)j * 10240;
  const float* pf = pfeat + (size_t)b * 8192;
  float acc = 0.f;
  for (int k = lane * 4; k < 8192; k += 256) {
    float4 a = *(const float4*)(pf + k);
    float4 w = *(const float4*)(wr + k);
    acc += a.x * w.x + a.y * w.y + a.z * w.z + a.w * w.w;
  }
  const float* rf = rfeat + (size_t)b * 2048;
  const float* wr2 = wr + 8192;
  for (int k = lane * 4; k < 2048; k += 256) {
    float4 a = *(const float4*)(rf + k);
    float4 w = *(const float4*)(wr2 + k);
    acc += a.x * w.x + a.y * w.y + a.z * w.z + a.w * w.w;
  }
#pragma unroll
  for (int off = 32; off > 0; off >>= 1) acc += __shfl_down(acc, off, 64);
  if (lane == 0) out[b * 200 + j] = acc + cb[j];
}

// ---------------------------------------------------------------------------
extern "C" void kernel_launch(void* const* d_in, const int* in_sizes, int n_in,
                              void* d_out, int out_size, void* d_ws, size_t ws_size,
                              hipStream_t stream) {
  const float* x   = (const float*)d_in[0];
  const float* bbw = (const float*)d_in[1];
  const float* bbb = (const float*)d_in[2];
  const float* w1  = (const float*)d_in[3];
  const float* b1  = (const float*)d_in[4];
  const float* t1w = (const float*)d_in[5];
  const float* t1b = (const float*)d_in[6];
  const float* w2  = (const float*)d_in[7];
  const float* b2  = (const float*)d_in[8];
  const float* t2w = (const float*)d_in[9];
  const float* t2b = (const float*)d_in[10];
  const float* w3  = (const float*)d_in[11];
  const float* b3  = (const float*)d_in[12];
  const float* t3w = (const float*)d_in[13];
  const float* t3b = (const float*)d_in[14];
  const float* cw  = (const float*)d_in[15];
  const float* cb  = (const float*)d_in[16];
  float* out = (float*)d_out;

  char* p = (char*)d_ws;
  auto alloc = [&](size_t bytes) -> char* {
    char* r = p; p += (bytes + 255) & ~(size_t)255; return r;
  };
  int*      anch  = (int*)     alloc((size_t)1614 * 4 * 4);
  float*    areas = (float*)   alloc((size_t)1614 * 4);
  float*    w1p   = (float*)   alloc((size_t)128 * 18432 * 4);
  _Float16* bWh   = (_Float16*)alloc((size_t)2048 * 3072 * 2);
  _Float16* bWl   = (_Float16*)alloc((size_t)2048 * 3072 * 2);
  _Float16* w1h   = (_Float16*)alloc((size_t)128 * 18432 * 2);
  _Float16* w1l   = (_Float16*)alloc((size_t)128 * 18432 * 2);
  _Float16* Ahh   = (_Float16*)alloc((size_t)1664 * 3072 * 2);
  _Float16* All   = (_Float16*)alloc((size_t)1664 * 3072 * 2);
  _Float16* rawh  = (_Float16*)alloc((size_t)1664 * 2048 * 2);
  _Float16* rawl  = (_Float16*)alloc((size_t)1664 * 2048 * 2);
  float*    raw   = (float*)   alloc((size_t)1568 * 2048 * 4);
  float*    w2p   = (float*)   alloc((size_t)128 * 9 * 128 * 4);
  float*    w3p   = (float*)   alloc((size_t)128 * 9 * 128 * 4);
  // P (split-K partials, 2x1664x2048 f32) aliases y1s (32x1568x128 f32):
  // lifetimes are stream-ordered disjoint (P: gemm->reduce; y1s: nav->y1_reduce).
  char*     big   = alloc((size_t)2 * 1664 * 2048 * 4);
  float*    Pbuf  = (float*)big;
  float*    y1s   = (float*)big;
  float*    y1v   = (float*)   alloc((size_t)1568 * 128 * 4);
  float*    y2v   = (float*)   alloc((size_t)392 * 128 * 4);
  float*    y3v   = (float*)   alloc((size_t)128 * 128 * 4);
  float*    sc    = (float*)   alloc((size_t)8 * 1614 * 4);
  int*      boxes = (int*)     alloc((size_t)8 * 4 * 4 * 4);
  float*    pfeat = (float*)   alloc((size_t)32 * 2048 * 4);
  float*    rfeat = (float*)   alloc((size_t)8 * 2048 * 4);

  anchors_kernel<<<7, 256, 0, stream>>>(anch, areas);
  permute_w<<<(128 * 9 * 2048 + 255) / 256, 256, 0, stream>>>(w1, w1p, 128, 2048);
  permute_w<<<(128 * 9 * 128 + 255) / 256, 256, 0, stream>>>(w2, w2p, 128, 128);
  permute_w<<<(128 * 9 * 128 + 255) / 256, 256, 0, stream>>>(w3, w3p, 128, 128);
  split_w<<<(2048 * 3072 / 8 + 255) / 256, 256, 0, stream>>>(bbw, bWh, bWl, 2048 * 3072 / 8);
  split_w<<<(128 * 18432 / 8 + 255) / 256, 256, 0, stream>>>(w1p, w1h, w1l, 128 * 18432 / 8);
  split_x<<<(1664 * 384 + 255) / 256, 256, 0, stream>>>(x, Ahh, All);

  gemm_bb_mfma<<<dim3(13, 16, 2), 256, 0, stream>>>(Ahh, All, bWh, bWl, Pbuf);
  bb_reduce<1><<<1664, 256, 0, stream>>>(Pbuf, bbb, raw, rawh, rawl);
  gemm_nav_mfma<<<dim3(13, 32), 256, 0, stream>>>(rawh, rawl, w1h, w1l, y1s);
  y1_reduce<<<(1568 * 128 + 255) / 256, 256, 0, stream>>>(y1s, b1, y1v);
  mean_kernel<<<64, 256, 0, stream>>>(raw, rfeat, 196);
  conv3x3s2<<<(8 * 7 * 7 * 128 + 255) / 256, 256, 0, stream>>>(y1v, w2p, b2, y2v, 14, 7);
  conv3x3s2<<<(8 * 4 * 4 * 128 + 255) / 256, 256, 0, stream>>>(y2v, w3p, b3, y3v, 7, 4);
  scores_kernel<<<(8 * 1614 + 255) / 256, 256, 0, stream>>>(
      y1v, y2v, y3v, t1w, t1b, t2w, t2b, t3w, t3b, sc);
  nms_kernel<<<8, 256, 0, stream>>>(sc, anch, areas, boxes);
  crop_kernel<<<(32 * 3 * 224 * 224) / 256, 256, 0, stream>>>(x, boxes, Ahh, All);
  gemm_bb_mfma<<<dim3(13, 16, 2), 256, 0, stream>>>(Ahh, All, bWh, bWl, Pbuf);
  bb_reduce<0><<<1568, 256, 0, stream>>>(Pbuf, bbb, raw, rawh, rawl);
  mean_kernel<<<256, 256, 0, stream>>>(raw, pfeat, 49);
  final_kernel<<<400, 256, 0, stream>>>(pfeat, rfeat, cw, cb, out);
}

// Round 5
// 391.467 us; speedup vs baseline: 4.1875x; 1.0619x over previous
//
#include <hip/hip_runtime.h>
#include <math.h>

// ---------------------------------------------------------------------------
// NTSNet forward. Big GEMMs on MFMA via 2-way f16 split (3 products: hh,hl,lh)
// R2: parallel means. R3: split-K GEMMs (occupancy). R4: 2-phase double-buffer
//     pipeline (issue-early staging) + bijective XCD-chunked block swizzle.
// ---------------------------------------------------------------------------

typedef _Float16 h8 __attribute__((ext_vector_type(8)));
typedef float f32x4 __attribute__((ext_vector_type(4)));

#define ASCALE 256.0f
#define WSCALE 16384.0f
#define RSCALE (1.0f / (256.0f * 16384.0f))

__device__ __forceinline__ void gload16(const void* g, void* l) {
  __builtin_amdgcn_global_load_lds(
      (__attribute__((address_space(1))) void*)(void*)(uintptr_t)g,
      (__attribute__((address_space(3))) void*)l, 16, 0, 0);
}

// ---------------- anchors (faithful port of _generate_default_anchor_maps) --
__global__ __launch_bounds__(256) void anchors_kernel(int* __restrict__ anch,
                                                      float* __restrict__ areas) {
  int i = blockIdx.x * 256 + threadIdx.x;
  if (i >= 1614) return;
  int stride, oh, a, pos;
  double size, sc;
  const double C13 = 1.2599210498948732;
  const double C23 = 1.5874010519681994;
  if (i < 1176) {
    stride = 32; size = 48.0; oh = 14; a = i / 196; pos = i % 196;
    sc = (a / 3 == 0) ? C13 : C23;
  } else if (i < 1470) {
    int r = i - 1176; stride = 64; size = 96.0; oh = 7; a = r / 49; pos = r % 49;
    sc = (a / 3 == 0) ? C13 : C23;
  } else {
    int r = i - 1470; stride = 128; size = 192.0; oh = 4; a = r / 16; pos = r % 16;
    int si = a / 3;
    sc = (si == 0) ? 1.0 : ((si == 1) ? C13 : C23);
  }
  int ari = a % 3;
  double ar = (ari == 0) ? 0.667 : ((ari == 1) ? 1.0 : 1.5);
  int gy = pos / oh, gx = pos % oh;
  float cy = 0.5f * (float)stride + (float)(stride * gy);
  float cx = 0.5f * (float)stride + (float)(stride * gx);
  double ss = sqrt(ar);
  double hd = (size * sc) / ss;
  double wd = (size * sc) * ss;
  float hh = (float)(hd * 0.5), wh = (float)(wd * 0.5);
  float e0 = (cy - hh) + 224.0f;
  float e1 = (cx - wh) + 224.0f;
  float e2 = (cy + hh) + 224.0f;
  float e3 = (cx + wh) + 224.0f;
  int y0 = (int)e0, x0 = (int)e1, y1i = (int)e2, x1i = (int)e3;
  anch[i * 4 + 0] = y0; anch[i * 4 + 1] = x0;
  anch[i * 4 + 2] = y1i; anch[i * 4 + 3] = x1i;
  areas[i] = (float)(y1i - y0) * (float)(x1i - x0);
}

// ---------------- weight permute: wp[o][tap][c] = w[o][c][tap] --------------
__global__ __launch_bounds__(256) void permute_w(const float* __restrict__ w,
                                                 float* __restrict__ wp,
                                                 int Cout, int Cin) {
  int idx = blockIdx.x * 256 + threadIdx.x;
  int total = Cout * 9 * Cin;
  if (idx >= total) return;
  int c = idx % Cin; int t2 = idx / Cin; int tap = t2 % 9; int o = t2 / 9;
  wp[idx] = w[(o * Cin + c) * 9 + tap];
}

// ---------------- f32 -> f16 hi/lo split (linear, scale WSCALE) -------------
__global__ __launch_bounds__(256) void split_w(const float* __restrict__ src,
                                               _Float16* __restrict__ h,
                                               _Float16* __restrict__ l, int n8) {
  int i = blockIdx.x * 256 + threadIdx.x;
  if (i >= n8) return;
  float4 v0 = *(const float4*)(src + (size_t)i * 8);
  float4 v1 = *(const float4*)(src + (size_t)i * 8 + 4);
  float vv[8] = {v0.x, v0.y, v0.z, v0.w, v1.x, v1.y, v1.z, v1.w};
  h8 vh, vl;
#pragma unroll
  for (int j = 0; j < 8; ++j) {
    float s = vv[j] * WSCALE;
    _Float16 a = (_Float16)s;
    vh[j] = a; vl[j] = (_Float16)(s - (float)a);
  }
  *(h8*)(h + (size_t)i * 8) = vh;
  *(h8*)(l + (size_t)i * 8) = vl;
}

// ---------------- x patchify -> A hi/lo [1664][3072] (scale ASCALE) ---------
__global__ __launch_bounds__(256) void split_x(const float* __restrict__ x,
                                               _Float16* __restrict__ Ah,
                                               _Float16* __restrict__ Al) {
  int i = blockIdx.x * 256 + threadIdx.x;
  if (i >= 1664 * 384) return;
  int kq = i % 384, m = i / 384;
  int k = kq * 8;
  h8 vh = {}, vl = {};
  if (m < 1568) {
    int b = m / 196, pos = m % 196;
    int c = k >> 10, r = (k >> 5) & 31, col = k & 31;
    int py = (pos / 14) * 32 + r, px = (pos % 14) * 32 + col;
    const float* sp2 = x + (((size_t)(b * 3 + c) * 448 + py) * 448 + px);
    float4 v0 = *(const float4*)sp2;
    float4 v1 = *(const float4*)(sp2 + 4);
    float vv[8] = {v0.x, v0.y, v0.z, v0.w, v1.x, v1.y, v1.z, v1.w};
#pragma unroll
    for (int j = 0; j < 8; ++j) {
      float s = vv[j] * ASCALE;
      _Float16 a = (_Float16)s;
      vh[j] = a; vl[j] = (_Float16)(s - (float)a);
    }
  }
  *(h8*)(Ah + (size_t)m * 3072 + k) = vh;
  *(h8*)(Al + (size_t)m * 3072 + k) = vl;
}

// ---------------- backbone GEMM (MFMA, f16-split, split-K=2, 2-phase dbuf) --
// Writes raw f32 dot-product partials P[z][1664][2048] (no scale/bias).
__global__ __launch_bounds__(256) void gemm_bb_mfma(
    const _Float16* __restrict__ Ah, const _Float16* __restrict__ Al,
    const _Float16* __restrict__ Bh, const _Float16* __restrict__ Bl,
    float* __restrict__ P) {
  __shared__ __align__(16) char lds[65536];  // 2 x (Ah|Al|Bh|Bl tiles, 8KB each)
  const int t = threadIdx.x;
  // XCD-chunked bijective swizzle: 208 blocks = 8 XCD x 26 (2 B-columns each).
  const int bid = blockIdx.x + 13 * blockIdx.y;
  const int orig = (bid & 7) * 26 + (bid >> 3);
  const int m0 = (orig % 13) * 128, n0 = (orig / 13) * 128;
  const int kz = blockIdx.z;
  const int lane = t & 63, w = t >> 6;
  const int wm = (w >> 1) * 64, wn = (w & 1) * 64;
  const int lrow = lane & 15, kg = lane >> 4;

  int offA[4], offB[4];
#pragma unroll
  for (int i = 0; i < 4; ++i) {
    int ba = (wm + i * 16 + lrow) * 64 + kg * 16;
    offA[i] = ba ^ (((ba >> 7) & 3) << 4);
    int bb2 = (wn + i * 16 + lrow) * 64 + kg * 16;
    offB[i] = bb2 ^ (((bb2 >> 7) & 3) << 4);
  }
  size_t gAo[2], gBo[2];
  int ldso[2];
#pragma unroll
  for (int e = 0; e < 2; ++e) {
    int p = e * 256 + t;
    int lsl = p ^ ((p >> 3) & 3);   // inverse swizzle (involution) in slot units
    int row = lsl >> 2, kq = lsl & 3;
    gAo[e] = (size_t)(m0 + row) * 3072 + kq * 8;
    gBo[e] = (size_t)(n0 + row) * 3072 + kq * 8;
    ldso[e] = e * 4096 + (t & 192) * 16;
  }

  auto STAGE = [&](int buf, int k0) {
    char* L = lds + buf * 32768;
#pragma unroll
    for (int e = 0; e < 2; ++e) {
      gload16(Ah + gAo[e] + k0, L + ldso[e]);
      gload16(Al + gAo[e] + k0, L + 8192 + ldso[e]);
      gload16(Bh + gBo[e] + k0, L + 16384 + ldso[e]);
      gload16(Bl + gBo[e] + k0, L + 24576 + ldso[e]);
    }
  };

  f32x4 acc[4][4] = {};
  const int kbeg = kz * 1536, kend = kbeg + 1536;
  STAGE(0, kbeg);
  __syncthreads();
  int cur = 0;
  for (int k0 = kbeg; k0 < kend; k0 += 32) {
    if (k0 + 32 < kend) STAGE(cur ^ 1, k0 + 32);  // issue-early: hides under MFMA
    const char* L = lds + cur * 32768;
    h8 fah[4], fal[4], fbh[4], fbl[4];
#pragma unroll
    for (int i = 0; i < 4; ++i) {
      fah[i] = *(const h8*)(L + offA[i]);
      fal[i] = *(const h8*)(L + 8192 + offA[i]);
      fbh[i] = *(const h8*)(L + 16384 + offB[i]);
      fbl[i] = *(const h8*)(L + 24576 + offB[i]);
    }
#pragma unroll
    for (int i = 0; i < 4; ++i)
#pragma unroll
      for (int j = 0; j < 4; ++j)
        acc[i][j] = __builtin_amdgcn_mfma_f32_16x16x32_f16(fah[i], fbh[j], acc[i][j], 0, 0, 0);
#pragma unroll
    for (int i = 0; i < 4; ++i)
#pragma unroll
      for (int j = 0; j < 4; ++j)
        acc[i][j] = __builtin_amdgcn_mfma_f32_16x16x32_f16(fah[i], fbl[j], acc[i][j], 0, 0, 0);
#pragma unroll
    for (int i = 0; i < 4; ++i)
#pragma unroll
      for (int j = 0; j < 4; ++j)
        acc[i][j] = __builtin_amdgcn_mfma_f32_16x16x32_f16(fal[i], fbh[j], acc[i][j], 0, 0, 0);
    __syncthreads();  // vmcnt(0)+barrier: next-tile stage landed, reads done
    cur ^= 1;
  }
  float* Pz = P + (size_t)kz * 1664 * 2048;
  const int prow = (lane >> 4) * 4;
#pragma unroll
  for (int i = 0; i < 4; ++i) {
#pragma unroll
    for (int j = 0; j < 4; ++j) {
      int n = n0 + wn + j * 16 + lrow;
#pragma unroll
      for (int r = 0; r < 4; ++r) {
        int m = m0 + wm + i * 16 + prow + r;
        Pz[(size_t)m * 2048 + n] = acc[i][j][r];
      }
    }
  }
}

// ---------------- split-K reduce: C = relu((p0+p1)*RSCALE + bias) -----------
// WRITE_SPLIT: also emit h/l f16 split (ASCALE) incl. zeroed rows 1568..1663.
template <int WRITE_SPLIT>
__global__ __launch_bounds__(256) void bb_reduce(const float* __restrict__ P,
                                                 const float* __restrict__ bias,
                                                 float* __restrict__ raw,
                                                 _Float16* __restrict__ h,
                                                 _Float16* __restrict__ l) {
  int idx = blockIdx.x * 256 + threadIdx.x;
  int m = idx >> 8, col = (idx & 255) * 8;
  if (WRITE_SPLIT) {
    if (m >= 1664) return;
    if (m >= 1568) {
      h8 z = {};
      *(h8*)(h + (size_t)m * 2048 + col) = z;
      *(h8*)(l + (size_t)m * 2048 + col) = z;
      return;
    }
  } else {
    if (m >= 1568) return;
  }
  size_t o = (size_t)m * 2048 + col;
  const float* p0 = P + o;
  const float* p1 = P + (size_t)1664 * 2048 + o;
  float4 a0 = *(const float4*)(p0);
  float4 a1 = *(const float4*)(p0 + 4);
  float4 c0 = *(const float4*)(p1);
  float4 c1 = *(const float4*)(p1 + 4);
  float4 b0 = *(const float4*)(bias + col);
  float4 b1 = *(const float4*)(bias + col + 4);
  float v[8];
  v[0] = fmaxf(fmaf(a0.x + c0.x, RSCALE, b0.x), 0.f);
  v[1] = fmaxf(fmaf(a0.y + c0.y, RSCALE, b0.y), 0.f);
  v[2] = fmaxf(fmaf(a0.z + c0.z, RSCALE, b0.z), 0.f);
  v[3] = fmaxf(fmaf(a0.w + c0.w, RSCALE, b0.w), 0.f);
  v[4] = fmaxf(fmaf(a1.x + c1.x, RSCALE, b1.x), 0.f);
  v[5] = fmaxf(fmaf(a1.y + c1.y, RSCALE, b1.y), 0.f);
  v[6] = fmaxf(fmaf(a1.z + c1.z, RSCALE, b1.z), 0.f);
  v[7] = fmaxf(fmaf(a1.w + c1.w, RSCALE, b1.w), 0.f);
  *(float4*)(raw + o) = make_float4(v[0], v[1], v[2], v[3]);
  *(float4*)(raw + o + 4) = make_float4(v[4], v[5], v[6], v[7]);
  if (WRITE_SPLIT) {
    h8 vh, vl;
#pragma unroll
    for (int j = 0; j < 8; ++j) {
      float s = v[j] * ASCALE;
      _Float16 a = (_Float16)s;
      vh[j] = a; vl[j] = (_Float16)(s - (float)a);
    }
    *(h8*)(h + o) = vh;
    *(h8*)(l + o) = vl;
  }
}

// ---------------- navigator y1 GEMM (MFMA f16-split, split-K=32, dbuf) ------
__global__ __launch_bounds__(256) void gemm_nav_mfma(
    const _Float16* __restrict__ Ah, const _Float16* __restrict__ Al,
    const _Float16* __restrict__ Bh, const _Float16* __restrict__ Bl,
    float* __restrict__ part) {
  __shared__ __align__(16) char lds[65536];
  const int t = threadIdx.x;
  // XCD-chunked bijective swizzle: 416 blocks = 8 XCD x 52 (4 B-slices each).
  const int bid = blockIdx.x + 13 * blockIdx.y;
  const int orig = (bid & 7) * 52 + (bid >> 3);
  const int m0 = (orig % 13) * 128;
  const int sp = orig / 13;  // 0..31
  const int lane = t & 63, w = t >> 6;
  const int wm = (w >> 1) * 64, wn = (w & 1) * 64;
  const int lrow = lane & 15, kg = lane >> 4;

  int offA[4], offB[4];
#pragma unroll
  for (int i = 0; i < 4; ++i) {
    int ba = (wm + i * 16 + lrow) * 64 + kg * 16;
    offA[i] = ba ^ (((ba >> 7) & 3) << 4);
    int bb2 = (wn + i * 16 + lrow) * 64 + kg * 16;
    offB[i] = bb2 ^ (((bb2 >> 7) & 3) << 4);
  }
  size_t gBo[2];
  int ldso[2], akq8[2], ab[2], apy[2], apx[2], amv[2];
#pragma unroll
  for (int e = 0; e < 2; ++e) {
    int p = e * 256 + t;
    int lsl = p ^ ((p >> 3) & 3);
    int row = lsl >> 2, kq = lsl & 3;
    gBo[e] = (size_t)row * 18432 + kq * 8;
    ldso[e] = e * 4096 + (t & 192) * 16;
    int m = m0 + row;
    amv[e] = (m < 1568);
    int b = m / 196, pos = m % 196;
    ab[e] = b; apy[e] = pos / 14; apx[e] = pos % 14;
    akq8[e] = kq * 8;
  }

  auto STAGE = [&](int buf, int k0) {
    const int tap = k0 >> 11;   // 32 | 2048: no tap straddle within a K-step
    const int c = k0 & 2047;
    const int dy = tap / 3 - 1, dx = tap % 3 - 1;
    char* L = lds + buf * 32768;
#pragma unroll
    for (int e = 0; e < 2; ++e) {
      int sy = apy[e] + dy, sx = apx[e] + dx;
      bool ok = amv[e] && ((unsigned)sy < 14u) && ((unsigned)sx < 14u);
      size_t rowi = ok ? (size_t)(ab[e] * 196 + sy * 14 + sx) : (size_t)1600;
      size_t ao = rowi * 2048 + c + akq8[e];
      gload16(Ah + ao, L + ldso[e]);
      gload16(Al + ao, L + 8192 + ldso[e]);
      gload16(Bh + gBo[e] + k0, L + 16384 + ldso[e]);
      gload16(Bl + gBo[e] + k0, L + 24576 + ldso[e]);
    }
  };

  f32x4 acc[4][4] = {};
  const int kbeg = sp * 576, kend = kbeg + 576;
  STAGE(0, kbeg);
  __syncthreads();
  int cur = 0;
  for (int k0 = kbeg; k0 < kend; k0 += 32) {
    if (k0 + 32 < kend) STAGE(cur ^ 1, k0 + 32);
    const char* L = lds + cur * 32768;
    h8 fah[4], fal[4], fbh[4], fbl[4];
#pragma unroll
    for (int i = 0; i < 4; ++i) {
      fah[i] = *(const h8*)(L + offA[i]);
      fal[i] = *(const h8*)(L + 8192 + offA[i]);
      fbh[i] = *(const h8*)(L + 16384 + offB[i]);
      fbl[i] = *(const h8*)(L + 24576 + offB[i]);
    }
#pragma unroll
    for (int i = 0; i < 4; ++i)
#pragma unroll
      for (int j = 0; j < 4; ++j)
        acc[i][j] = __builtin_amdgcn_mfma_f32_16x16x32_f16(fah[i], fbh[j], acc[i][j], 0, 0, 0);
#pragma unroll
    for (int i = 0; i < 4; ++i)
#pragma unroll
      for (int j = 0; j < 4; ++j)
        acc[i][j] = __builtin_amdgcn_mfma_f32_16x16x32_f16(fah[i], fbl[j], acc[i][j], 0, 0, 0);
#pragma unroll
    for (int i = 0; i < 4; ++i)
#pragma unroll
      for (int j = 0; j < 4; ++j)
        acc[i][j] = __builtin_amdgcn_mfma_f32_16x16x32_f16(fal[i], fbh[j], acc[i][j], 0, 0, 0);
    __syncthreads();
    cur ^= 1;
  }
  const int prow = (lane >> 4) * 4;
#pragma unroll
  for (int i = 0; i < 4; ++i) {
#pragma unroll
    for (int j = 0; j < 4; ++j) {
      int n = wn + j * 16 + lrow;
#pragma unroll
      for (int r = 0; r < 4; ++r) {
        int m = m0 + wm + i * 16 + prow + r;
        if (m < 1568)
          part[((size_t)sp * 1568 + m) * 128 + n] = acc[i][j][r] * RSCALE;
      }
    }
  }
}

__global__ __launch_bounds__(256) void y1_reduce(const float* __restrict__ part,
                                                 const float* __restrict__ b1,
                                                 float* __restrict__ y1) {
  int idx = blockIdx.x * 256 + threadIdx.x;
  if (idx >= 1568 * 128) return;
  int o = idx & 127;
  float s = b1[o];
#pragma unroll
  for (int sp = 0; sp < 32; ++sp) s += part[(size_t)sp * 1568 * 128 + idx];
  y1[idx] = fmaxf(s, 0.f);
}

// ---------------- small 3x3 stride-2 pad-1 convs (128->128 ch, NHWC) --------
__global__ __launch_bounds__(256) void conv3x3s2(const float* __restrict__ in,
                                                 const float* __restrict__ wp,
                                                 const float* __restrict__ bias,
                                                 float* __restrict__ out,
                                                 int Hin, int Hout) {
  int idx = blockIdx.x * 256 + threadIdx.x;
  int total = 8 * Hout * Hout * 128;
  if (idx >= total) return;
  int o = idx & 127; int pos = idx >> 7;
  int ox = pos % Hout; int t2 = pos / Hout; int oy = t2 % Hout; int b = t2 / Hout;
  float acc = bias[o];
  for (int dy = 0; dy < 3; ++dy) {
    int iy = 2 * oy - 1 + dy;
    if (iy < 0 || iy >= Hin) continue;
    for (int dx = 0; dx < 3; ++dx) {
      int ix = 2 * ox - 1 + dx;
      if (ix < 0 || ix >= Hin) continue;
      const float* ip = in + ((b * Hin + iy) * Hin + ix) * 128;
      const float* wgt = wp + (o * 9 + dy * 3 + dx) * 128;
#pragma unroll 4
      for (int c = 0; c < 128; c += 4) {
        float4 a = *(const float4*)(ip + c);
        float4 ww = *(const float4*)(wgt + c);
        acc += a.x * ww.x + a.y * ww.y + a.z * ww.z + a.w * ww.w;
      }
    }
  }
  out[idx] = fmaxf(acc, 0.f);
}

// ---------------- rpn scores ------------------------------------------------
__global__ __launch_bounds__(256) void scores_kernel(
    const float* __restrict__ y1, const float* __restrict__ y2,
    const float* __restrict__ y3, const float* __restrict__ t1w,
    const float* __restrict__ t1b, const float* __restrict__ t2w,
    const float* __restrict__ t2b, const float* __restrict__ t3w,
    const float* __restrict__ t3b, float* __restrict__ scores) {
  int idx = blockIdx.x * 256 + threadIdx.x;
  if (idx >= 8 * 1614) return;
  int b = idx / 1614, sI = idx % 1614;
  const float* f; const float* w; float bias;
  if (sI < 1176) {
    int a = sI / 196;
    f = y1 + (b * 196 + (sI % 196)) * 128; w = t1w + a * 128; bias = t1b[a];
  } else if (sI < 1470) {
    int r = sI - 1176; int a = r / 49;
    f = y2 + (b * 49 + (r % 49)) * 128; w = t2w + a * 128; bias = t2b[a];
  } else {
    int r = sI - 1470; int a = r / 16;
    f = y3 + (b * 16 + (r % 16)) * 128; w = t3w + a * 128; bias = t3b[a];
  }
  float acc = 0.f;
  for (int c = 0; c < 128; c += 4) {
    float4 a4 = *(const float4*)(f + c);
    float4 w4 = *(const float4*)(w + c);
    acc += a4.x * w4.x + a4.y * w4.y + a4.z * w4.z + a4.w * w4.w;
  }
  scores[idx] = acc + bias;
}

// ---------------- greedy NMS (per batch block) ------------------------------
__global__ __launch_bounds__(256) void nms_kernel(const float* __restrict__ scores,
                                                  const int* __restrict__ anch,
                                                  const float* __restrict__ areas,
                                                  int* __restrict__ boxes) {
  const int b = blockIdx.x, t = threadIdx.x;
  const float* s = scores + b * 1614;
  __shared__ unsigned char valid[1614];
  __shared__ float rv[256];
  __shared__ int ri[256];
  for (int i = t; i < 1614; i += 256) valid[i] = 1;
  __syncthreads();
  for (int n = 0; n < 4; ++n) {
    float best = -INFINITY; int bi = 0x7fffffff;
    for (int i = t; i < 1614; i += 256) {
      if (valid[i]) {
        float v = s[i];
        if (v > best || (v == best && i < bi)) { best = v; bi = i; }
      }
    }
    rv[t] = best; ri[t] = bi;
    __syncthreads();
    for (int off = 128; off > 0; off >>= 1) {
      if (t < off) {
        float ov = rv[t + off]; int oi = ri[t + off];
        if (ov > rv[t] || (ov == rv[t] && oi < ri[t])) { rv[t] = ov; ri[t] = oi; }
      }
      __syncthreads();
    }
    int sel = ri[0];
    if (sel > 1613) sel = 0;
    const int4 bb = ((const int4*)anch)[sel];
    const float Ai = areas[sel];
    if (t == 0) ((int4*)boxes)[b * 4 + n] = bb;
    __syncthreads();
    for (int i = t; i < 1614; i += 256) {
      if (!valid[i]) continue;
      const int4 ab = ((const int4*)anch)[i];
      float sy = fmaxf((float)ab.x, (float)bb.x);
      float sx = fmaxf((float)ab.y, (float)bb.y);
      float ey = fminf((float)ab.z, (float)bb.z);
      float ex = fminf((float)ab.w, (float)bb.w);
      float ly = ey - sy, lx = ex - sx;
      float inter = (ly < 0.f || lx < 0.f) ? 0.f : ly * lx;
      float iou = inter / (areas[i] + Ai - inter);
      if (iou >= 0.25f) valid[i] = 0;
    }
    __syncthreads();
  }
}

// ---------------- bilinear crop -> A hi/lo (im2col layout, scaled) ----------
__global__ __launch_bounds__(256) void crop_kernel(const float* __restrict__ x,
                                                   const int* __restrict__ boxes,
                                                   _Float16* __restrict__ Ah,
                                                   _Float16* __restrict__ Al) {
  int idx = blockIdx.x * 256 + threadIdx.x;
  if (idx >= 32 * 3 * 224 * 224) return;
  int px = idx % 224; int t1 = idx / 224; int py = t1 % 224; int t2 = t1 / 224;
  int c = t2 % 3; int p = t2 / 3;
  int b = p >> 2;
  const int4 bb = ((const int4*)boxes)[p];
  float ty = (float)py / 223.0f;
  float txf = (float)px / 223.0f;
  float ys = (float)bb.x + ty * (float)(bb.z - bb.x - 1);
  float xs = (float)bb.y + txf * (float)(bb.w - bb.y - 1);
  float yf = floorf(ys), xf = floorf(xs);
  float wy = ys - yf, wx = xs - xf;
  int yl = (int)yf, xl = (int)xf;
  int yh = min(yl + 1, 895), xh = min(xl + 1, 895);
  const float* img = x + (size_t)(b * 3 + c) * 448 * 448;
  auto samp = [&](int yy, int xx) -> float {
    yy -= 224; xx -= 224;
    if (yy < 0 || yy >= 448 || xx < 0 || xx >= 448) return 0.f;
    return img[yy * 448 + xx];
  };
  float v00 = samp(yl, xl), v01 = samp(yl, xh);
  float v10 = samp(yh, xl), v11 = samp(yh, xh);
  float top = v00 * (1.f - wx) + v01 * wx;
  float bot = v10 * (1.f - wx) + v11 * wx;
  float val = top * (1.f - wy) + bot * wy;
  int i = py >> 5, r = py & 31, j = px >> 5, col = px & 31;
  int m = p * 49 + i * 7 + j;
  int k = (c << 10) + (r << 5) + col;
  float s = val * ASCALE;
  _Float16 a = (_Float16)s;
  Ah[(size_t)m * 3072 + k] = a;
  Al[(size_t)m * 3072 + k] = (_Float16)(s - (float)a);
}

// ---------------- parallel spatial mean -------------------------------------
// grid.x = groups * 8; block handles one group x 256 consecutive columns.
__global__ __launch_bounds__(256) void mean_kernel(const float* __restrict__ in,
                                                   float* __restrict__ out,
                                                   int rows) {
  int g = blockIdx.x >> 3;
  int o = ((blockIdx.x & 7) << 8) + threadIdx.x;
  const float* base = in + ((size_t)g * rows) * 2048 + o;
  float s0 = 0.f, s1 = 0.f, s2 = 0.f, s3 = 0.f;
  int r = 0;
  for (; r + 4 <= rows; r += 4) {
    s0 += base[(size_t)(r + 0) * 2048];
    s1 += base[(size_t)(r + 1) * 2048];
    s2 += base[(size_t)(r + 2) * 2048];
    s3 += base[(size_t)(r + 3) * 2048];
  }
  for (; r < rows; ++r) s0 += base[(size_t)r * 2048];
  out[(size_t)g * 2048 + o] = ((s0 + s1) + (s2 + s3)) / (float)rows;
}

// ---------------- final linear: one wave per (b, class) ---------------------
__global__ __launch_bounds__(256) void final_kernel(const float* __restrict__ pfeat,
                                                    const float* __restrict__ rfeat,
                                                    const float* __restrict__ cw,
                                                    const float* __restrict__ cb,
                                                    float* __restrict__ out) {
  int gw = (blockIdx.x * 256 + threadIdx.x) >> 6;
  int lane = threadIdx.x & 63;
  if (gw >= 1600) return;
  int b = gw / 200, j = gw % 200;
  const float* wr = cw + (size_t)j * 10240;
  const float* pf = pfeat + (size_t)b * 8192;
  float acc = 0.f;
  for (int k = lane * 4; k < 8192; k += 256) {
    float4 a = *(const float4*)(pf + k);
    float4 w = *(const float4*)(wr + k);
    acc += a.x * w.x + a.y * w.y + a.z * w.z + a.w * w.w;
  }
  const float* rf = rfeat + (size_t)b * 2048;
  const float* wr2 = wr + 8192;
  for (int k = lane * 4; k < 2048; k += 256) {
    float4 a = *(const float4*)(rf + k);
    float4 w = *(const float4*)(wr2 + k);
    acc += a.x * w.x + a.y * w.y + a.z * w.z + a.w * w.w;
  }
#pragma unroll
  for (int off = 32; off > 0; off >>= 1) acc += __shfl_down(acc, off, 64);
  if (lane == 0) out[b * 200 + j] = acc + cb[j];
}

// ---------------------------------------------------------------------------
extern "C" void kernel_launch(void* const* d_in, const int* in_sizes, int n_in,
                              void* d_out, int out_size, void* d_ws, size_t ws_size,
                              hipStream_t stream) {
  const float* x   = (const float*)d_in[0];
  const float* bbw = (const float*)d_in[1];
  const float* bbb = (const float*)d_in[2];
  const float* w1  = (const float*)d_in[3];
  const float* b1  = (const float*)d_in[4];
  const float* t1w = (const float*)d_in[5];
  const float* t1b = (const float*)d_in[6];
  const float* w2  = (const float*)d_in[7];
  const float* b2  = (const float*)d_in[8];
  const float* t2w = (const float*)d_in[9];
  const float* t2b = (const float*)d_in[10];
  const float* w3  = (const float*)d_in[11];
  const float* b3  = (const float*)d_in[12];
  const float* t3w = (const float*)d_in[13];
  const float* t3b = (const float*)d_in[14];
  const float* cw  = (const float*)d_in[15];
  const float* cb  = (const float*)d_in[16];
  float* out = (float*)d_out;

  char* p = (char*)d_ws;
  auto alloc = [&](size_t bytes) -> char* {
    char* r = p; p += (bytes + 255) & ~(size_t)255; return r;
  };
  int*      anch  = (int*)     alloc((size_t)1614 * 4 * 4);
  float*    areas = (float*)   alloc((size_t)1614 * 4);
  float*    w1p   = (float*)   alloc((size_t)128 * 18432 * 4);
  _Float16* bWh   = (_Float16*)alloc((size_t)2048 * 3072 * 2);
  _Float16* bWl   = (_Float16*)alloc((size_t)2048 * 3072 * 2);
  _Float16* w1h   = (_Float16*)alloc((size_t)128 * 18432 * 2);
  _Float16* w1l   = (_Float16*)alloc((size_t)128 * 18432 * 2);
  _Float16* Ahh   = (_Float16*)alloc((size_t)1664 * 3072 * 2);
  _Float16* All   = (_Float16*)alloc((size_t)1664 * 3072 * 2);
  _Float16* rawh  = (_Float16*)alloc((size_t)1664 * 2048 * 2);
  _Float16* rawl  = (_Float16*)alloc((size_t)1664 * 2048 * 2);
  float*    raw   = (float*)   alloc((size_t)1568 * 2048 * 4);
  float*    w2p   = (float*)   alloc((size_t)128 * 9 * 128 * 4);
  float*    w3p   = (float*)   alloc((size_t)128 * 9 * 128 * 4);
  // P (split-K partials, 2x1664x2048 f32) aliases y1s (32x1568x128 f32):
  // lifetimes are stream-ordered disjoint (P: gemm->reduce; y1s: nav->y1_reduce).
  char*     big   = alloc((size_t)2 * 1664 * 2048 * 4);
  float*    Pbuf  = (float*)big;
  float*    y1s   = (float*)big;
  float*    y1v   = (float*)   alloc((size_t)1568 * 128 * 4);
  float*    y2v   = (float*)   alloc((size_t)392 * 128 * 4);
  float*    y3v   = (float*)   alloc((size_t)128 * 128 * 4);
  float*    sc    = (float*)   alloc((size_t)8 * 1614 * 4);
  int*      boxes = (int*)     alloc((size_t)8 * 4 * 4 * 4);
  float*    pfeat = (float*)   alloc((size_t)32 * 2048 * 4);
  float*    rfeat = (float*)   alloc((size_t)8 * 2048 * 4);

  anchors_kernel<<<7, 256, 0, stream>>>(anch, areas);
  permute_w<<<(128 * 9 * 2048 + 255) / 256, 256, 0, stream>>>(w1, w1p, 128, 2048);
  permute_w<<<(128 * 9 * 128 + 255) / 256, 256, 0, stream>>>(w2, w2p, 128, 128);
  permute_w<<<(128 * 9 * 128 + 255) / 256, 256, 0, stream>>>(w3, w3p, 128, 128);
  split_w<<<(2048 * 3072 / 8 + 255) / 256, 256, 0, stream>>>(bbw, bWh, bWl, 2048 * 3072 / 8);
  split_w<<<(128 * 18432 / 8 + 255) / 256, 256, 0, stream>>>(w1p, w1h, w1l, 128 * 18432 / 8);
  split_x<<<(1664 * 384 + 255) / 256, 256, 0, stream>>>(x, Ahh, All);

  gemm_bb_mfma<<<dim3(13, 16, 2), 256, 0, stream>>>(Ahh, All, bWh, bWl, Pbuf);
  bb_reduce<1><<<1664, 256, 0, stream>>>(Pbuf, bbb, raw, rawh, rawl);
  gemm_nav_mfma<<<dim3(13, 32), 256, 0, stream>>>(rawh, rawl, w1h, w1l, y1s);
  y1_reduce<<<(1568 * 128 + 255) / 256, 256, 0, stream>>>(y1s, b1, y1v);
  mean_kernel<<<64, 256, 0, stream>>>(raw, rfeat, 196);
  conv3x3s2<<<(8 * 7 * 7 * 128 + 255) / 256, 256, 0, stream>>>(y1v, w2p, b2, y2v, 14, 7);
  conv3x3s2<<<(8 * 4 * 4 * 128 + 255) / 256, 256, 0, stream>>>(y2v, w3p, b3, y3v, 7, 4);
  scores_kernel<<<(8 * 1614 + 255) / 256, 256, 0, stream>>>(
      y1v, y2v, y3v, t1w, t1b, t2w, t2b, t3w, t3b, sc);
  nms_kernel<<<8, 256, 0, stream>>>(sc, anch, areas, boxes);
  crop_kernel<<<(32 * 3 * 224 * 224) / 256, 256, 0, stream>>>(x, boxes, Ahh, All);
  gemm_bb_mfma<<<dim3(13, 16, 2), 256, 0, stream>>>(Ahh, All, bWh, bWl, Pbuf);
  bb_reduce<0><<<1568, 256, 0, stream>>>(Pbuf, bbb, raw, rawh, rawl);
  mean_kernel<<<256, 256, 0, stream>>>(raw, pfeat, 49);
  final_kernel<<<400, 256, 0, stream>>>(pfeat, rfeat, cw, cb, out);
}